// Round 1
// baseline (923.847 us; speedup 1.0000x reference)
//
#include <hip/hip_runtime.h>

#define N_NODES  50000
#define N_EDGES  1600000
#define DIM      128
#define N_GRAPHS 512

// ---------------------------------------------------------------------------
// CSR build: histogram of dst, exclusive scan, scatter src into buckets
// ---------------------------------------------------------------------------
__global__ void hist_kernel(const int* __restrict__ dst, int* __restrict__ deg) {
    int e = blockIdx.x * 256 + threadIdx.x;
    if (e < N_EDGES) atomicAdd(&deg[dst[e]], 1);
}

__global__ void scan_kernel(const int* __restrict__ deg, int* __restrict__ row_start) {
    __shared__ int tmp[1024];
    __shared__ int carry_s;
    int t = threadIdx.x;
    if (t == 0) { carry_s = 0; row_start[0] = 0; }
    __syncthreads();
    for (int base = 0; base < N_NODES; base += 1024) {
        int i = base + t;
        int v = (i < N_NODES) ? deg[i] : 0;
        tmp[t] = v;
        __syncthreads();
        for (int off = 1; off < 1024; off <<= 1) {
            int add = (t >= off) ? tmp[t - off] : 0;
            __syncthreads();
            tmp[t] += add;
            __syncthreads();
        }
        int inc = tmp[t] + carry_s;          // carry_s stable from prev tile
        if (i < N_NODES) row_start[i + 1] = inc;
        __syncthreads();                      // all reads of carry_s done
        if (t == 1023) carry_s = inc;
        __syncthreads();
    }
}

__global__ void scatter_kernel(const int* __restrict__ src, const int* __restrict__ dst,
                               const int* __restrict__ row_start, int* __restrict__ cursor,
                               int* __restrict__ ebuf) {
    int e = blockIdx.x * 256 + threadIdx.x;
    if (e < N_EDGES) {
        int d = dst[e];
        int pos = atomicAdd(&cursor[d], 1);
        ebuf[row_start[d] + pos] = src[e];
    }
}

// ---------------------------------------------------------------------------
// Mean aggregation: one wave (64 lanes) per node, lane holds 2 features.
// Edge indices loaded cooperatively (64 at a time) and broadcast via shuffle.
// ---------------------------------------------------------------------------
__global__ __launch_bounds__(256) void agg_kernel(const float* __restrict__ xin,
                                                  const int* __restrict__ row_start,
                                                  const int* __restrict__ ebuf,
                                                  float* __restrict__ agg) {
    int node = blockIdx.x * 4 + (threadIdx.x >> 6);
    if (node >= N_NODES) return;
    int lane = threadIdx.x & 63;
    int s = row_start[node], e = row_start[node + 1];
    float ax = 0.f, ay = 0.f;
    const float2* x2 = (const float2*)xin;
    for (int i = s; i < e; i += 64) {
        int nloc = e - i; if (nloc > 64) nloc = 64;
        int src_l = (i + lane < e) ? ebuf[i + lane] : 0;
        for (int j = 0; j < nloc; j++) {
            int src = __shfl(src_l, j, 64);
            float2 v = x2[(size_t)src * 64 + lane];
            ax += v.x; ay += v.y;
        }
    }
    float inv = (e > s) ? 1.0f / (float)(e - s) : 0.0f;  // deg==0 -> agg = 0
    float2 o; o.x = ax * inv; o.y = ay * inv;
    ((float2*)agg)[(size_t)node * 64 + lane] = o;
}

// ---------------------------------------------------------------------------
// Fused layer GEMM: xout = relu(agg @ Wl^T + xin @ Wr^T + b)
// Block: 256 threads, tile 32 rows x 128 cols. Thread: 4 rows x 4 cols.
// Weights staged in LDS in 32-k chunks ([128][36] pad -> 4-way worst conflict).
// Inputs read from global (broadcast address per half-wave -> L1/L2 hit).
// ---------------------------------------------------------------------------
__global__ __launch_bounds__(256) void sage_gemm(const float* __restrict__ agg,
                                                 const float* __restrict__ xin,
                                                 const float* __restrict__ Wl,
                                                 const float* __restrict__ Wr,
                                                 const float* __restrict__ bias,
                                                 float* __restrict__ xout, int nrows) {
    __shared__ float wl_s[128][36];
    __shared__ float wr_s[128][36];
    int t = threadIdx.x;
    int r_base = blockIdx.x * 32 + (t >> 5) * 4;
    int c_lo = t & 31;
    float acc[4][4];
    #pragma unroll
    for (int r = 0; r < 4; r++)
        #pragma unroll
        for (int c = 0; c < 4; c++) acc[r][c] = 0.f;

    for (int kc = 0; kc < DIM; kc += 32) {
        __syncthreads();  // protect previous chunk's reads
        for (int i = t; i < 128 * 8; i += 256) {   // 128 c-rows x 8 float4
            int c = i >> 3, k4 = i & 7;
            float4 wv  = ((const float4*)(Wl + c * DIM + kc))[k4];
            float4 wv2 = ((const float4*)(Wr + c * DIM + kc))[k4];
            *((float4*)&wl_s[c][k4 * 4]) = wv;
            *((float4*)&wr_s[c][k4 * 4]) = wv2;
        }
        __syncthreads();
        for (int k4 = 0; k4 < 8; k4++) {
            float4 av[4], xv[4];
            #pragma unroll
            for (int r = 0; r < 4; r++) {
                int row = r_base + r; if (row > nrows - 1) row = nrows - 1;
                av[r] = ((const float4*)(agg + (size_t)row * DIM + kc))[k4];
                xv[r] = ((const float4*)(xin + (size_t)row * DIM + kc))[k4];
            }
            #pragma unroll
            for (int cc = 0; cc < 4; cc++) {
                int c = c_lo + cc * 32;
                float4 wl4 = *((const float4*)&wl_s[c][k4 * 4]);
                float4 wr4 = *((const float4*)&wr_s[c][k4 * 4]);
                #pragma unroll
                for (int r = 0; r < 4; r++) {
                    acc[r][cc] += av[r].x * wl4.x + av[r].y * wl4.y
                                + av[r].z * wl4.z + av[r].w * wl4.w
                                + xv[r].x * wr4.x + xv[r].y * wr4.y
                                + xv[r].z * wr4.z + xv[r].w * wr4.w;
                }
            }
        }
    }
    #pragma unroll
    for (int cc = 0; cc < 4; cc++) {
        int c = c_lo + cc * 32;
        float bv = bias[c];
        #pragma unroll
        for (int r = 0; r < 4; r++) {
            int row = r_base + r;
            if (row < nrows) {
                float v = acc[r][cc] + bv;
                xout[(size_t)row * DIM + c] = fmaxf(v, 0.f);
            }
        }
    }
}

// ---------------------------------------------------------------------------
// Graph boundaries from sorted batch; then fused mean-pool + FC (wave/graph).
// ---------------------------------------------------------------------------
__global__ void graph_bounds(const int* __restrict__ batch, int* __restrict__ gstart) {
    int i = blockIdx.x * 256 + threadIdx.x;
    if (i < N_NODES) {
        int b = batch[i];
        int prev = (i == 0) ? -1 : batch[i - 1];
        for (int g = prev + 1; g <= b; g++) gstart[g] = i;
        if (i == 0) {
            int last = batch[N_NODES - 1];
            for (int g = last + 1; g <= N_GRAPHS; g++) gstart[g] = N_NODES;
        }
    }
}

__global__ __launch_bounds__(256) void pool_fc(const float* __restrict__ x,
                                               const int* __restrict__ gstart,
                                               const float* __restrict__ fc_w,
                                               const float* __restrict__ fc_b,
                                               float* __restrict__ out) {
    int g = blockIdx.x * 4 + (threadIdx.x >> 6);
    if (g >= N_GRAPHS) return;
    int lane = threadIdx.x & 63;
    int s = gstart[g], e = gstart[g + 1];
    float2 acc; acc.x = 0.f; acc.y = 0.f;
    const float2* x2 = (const float2*)x;
    for (int i = s; i < e; i++) {
        float2 v = x2[(size_t)i * 64 + lane];
        acc.x += v.x; acc.y += v.y;
    }
    float inv = (e > s) ? 1.0f / (float)(e - s) : 0.0f;
    const float2* w2 = (const float2*)fc_w;
    float2 w = w2[lane];
    float sres = (acc.x * w.x + acc.y * w.y) * inv;
    for (int off = 32; off; off >>= 1) sres += __shfl_down(sres, off, 64);
    if (lane == 0) out[g] = sres + fc_b[0];
}

// ---------------------------------------------------------------------------
extern "C" void kernel_launch(void* const* d_in, const int* in_sizes, int n_in,
                              void* d_out, int out_size, void* d_ws, size_t ws_size,
                              hipStream_t stream) {
    const float* x     = (const float*)d_in[0];
    const int*   ei    = (const int*)d_in[1];     // [2, E] int32
    const int*   batch = (const int*)d_in[2];
    const float* Wl[3] = {(const float*)d_in[3], (const float*)d_in[6], (const float*)d_in[9]};
    const float* bb[3] = {(const float*)d_in[4], (const float*)d_in[7], (const float*)d_in[10]};
    const float* Wr[3] = {(const float*)d_in[5], (const float*)d_in[8], (const float*)d_in[11]};
    const float* fc_w  = (const float*)d_in[12];
    const float* fc_b  = (const float*)d_in[13];
    float* out = (float*)d_out;

    char* p = (char*)d_ws;
    auto alloc = [&](size_t bytes) { char* r = p; p += (bytes + 255) & ~255ull; return r; };
    int* deg       = (int*)alloc((size_t)N_NODES * 4);
    int* cursor    = (int*)alloc((size_t)N_NODES * 4);
    int* row_start = (int*)alloc((size_t)(N_NODES + 1) * 4);
    int* ebuf      = (int*)alloc((size_t)N_EDGES * 4);
    int* gstart    = (int*)alloc((size_t)(N_GRAPHS + 1) * 4);
    float* agg     = (float*)alloc((size_t)N_NODES * DIM * 4);
    float* xb0     = (float*)alloc((size_t)N_NODES * DIM * 4);
    float* xb1     = (float*)alloc((size_t)N_NODES * DIM * 4);

    hipMemsetAsync(deg, 0, (size_t)N_NODES * 4, stream);
    hipMemsetAsync(cursor, 0, (size_t)N_NODES * 4, stream);

    hist_kernel<<<(N_EDGES + 255) / 256, 256, 0, stream>>>(ei + N_EDGES, deg);
    scan_kernel<<<1, 1024, 0, stream>>>(deg, row_start);
    scatter_kernel<<<(N_EDGES + 255) / 256, 256, 0, stream>>>(ei, ei + N_EDGES, row_start, cursor, ebuf);
    graph_bounds<<<(N_NODES + 255) / 256, 256, 0, stream>>>(batch, gstart);

    const float* xin = x;
    float* xout = xb0;
    for (int l = 0; l < 3; l++) {
        agg_kernel<<<(N_NODES + 3) / 4, 256, 0, stream>>>(xin, row_start, ebuf, agg);
        sage_gemm<<<(N_NODES + 31) / 32, 256, 0, stream>>>(agg, xin, Wl[l], Wr[l], bb[l], xout, N_NODES);
        xin = xout;
        xout = (xout == xb0) ? xb1 : xb0;
    }
    pool_fc<<<(N_GRAPHS + 3) / 4, 256, 0, stream>>>(xin, gstart, fc_w, fc_b, out);
}

// Round 2
// 712.932 us; speedup vs baseline: 1.2958x; 1.2958x over previous
//
#include <hip/hip_runtime.h>

#define N_NODES  50000
#define N_EDGES  1600000
#define DIM      128
#define N_GRAPHS 512
#define SCAN_BLOCK 1024
#define N_SBLK ((N_NODES + SCAN_BLOCK - 1) / SCAN_BLOCK)   // 49

typedef unsigned int uint_t;
typedef unsigned short ushort_t;

__device__ inline uint_t bf_rne(float f) {   // fp32 -> bf16 bits, round-nearest-even
    uint_t u = __float_as_uint(f);
    return (u + 0x7fffu + ((u >> 16) & 1u)) >> 16;
}

// ---------------------------------------------------------------------------
// CSR build: histogram of dst, hierarchical exclusive scan, scatter src
// ---------------------------------------------------------------------------
__global__ void hist_kernel(const int* __restrict__ dst, int* __restrict__ deg) {
    int e = blockIdx.x * 256 + threadIdx.x;
    if (e < N_EDGES) atomicAdd(&deg[dst[e]], 1);
}

__global__ void block_reduce(const int* __restrict__ deg, int* __restrict__ bsum) {
    __shared__ int red[256];
    int b = blockIdx.x, t = threadIdx.x;
    int base = b * SCAN_BLOCK;
    int s = 0;
    for (int i = t; i < SCAN_BLOCK; i += 256) {
        int idx = base + i;
        s += (idx < N_NODES) ? deg[idx] : 0;
    }
    red[t] = s; __syncthreads();
    for (int off = 128; off; off >>= 1) {
        if (t < off) red[t] += red[t + off];
        __syncthreads();
    }
    if (t == 0) bsum[b] = red[0];
}

__global__ void scan_tops(const int* __restrict__ bsum, int* __restrict__ bofs) {
    if (threadIdx.x == 0) {
        int acc = 0;
        for (int i = 0; i < N_SBLK; i++) { bofs[i] = acc; acc += bsum[i]; }
    }
}

__global__ void block_scan(const int* __restrict__ deg, const int* __restrict__ bofs,
                           int* __restrict__ row_start) {
    __shared__ int tmp[SCAN_BLOCK];
    int b = blockIdx.x, t = threadIdx.x;
    int i = b * SCAN_BLOCK + t;
    tmp[t] = (i < N_NODES) ? deg[i] : 0;
    __syncthreads();
    for (int off = 1; off < SCAN_BLOCK; off <<= 1) {
        int add = (t >= off) ? tmp[t - off] : 0;
        __syncthreads();
        tmp[t] += add;
        __syncthreads();
    }
    if (i < N_NODES) row_start[i + 1] = tmp[t] + bofs[b];
    if (i == 0) row_start[0] = 0;
}

__global__ void scatter_kernel(const int* __restrict__ src, const int* __restrict__ dst,
                               const int* __restrict__ row_start, int* __restrict__ cursor,
                               int* __restrict__ ebuf) {
    int e = blockIdx.x * 256 + threadIdx.x;
    if (e < N_EDGES) {
        int d = dst[e];
        int pos = atomicAdd(&cursor[d], 1);
        ebuf[row_start[d] + pos] = src[e];
    }
}

// ---------------------------------------------------------------------------
// fp32 -> bf16 conversion (layer-0 input only)
// ---------------------------------------------------------------------------
__global__ void f32_to_bf16(const float* __restrict__ in, ushort_t* __restrict__ out) {
    int i = blockIdx.x * 256 + threadIdx.x;          // i indexes groups of 4
    if (i < (N_NODES * DIM) / 4) {
        float4 v = ((const float4*)in)[i];
        uint2 o;
        o.x = bf_rne(v.x) | (bf_rne(v.y) << 16);
        o.y = bf_rne(v.z) | (bf_rne(v.w) << 16);
        ((uint2*)out)[i] = o;
    }
}

// ---------------------------------------------------------------------------
// Mean aggregation over bf16 features: one wave per node.
// Half-wave h handles edge slots 2j+h (interleaved -> balanced for small deg);
// lane&31 holds 4 features (uint2 = 8 B load). fp32 accumulate; halves merged
// by shuffle at the end; lanes 0-31 write float4.
// ---------------------------------------------------------------------------
__global__ __launch_bounds__(256) void agg_kernel(const ushort_t* __restrict__ xb,
                                                  const int* __restrict__ row_start,
                                                  const int* __restrict__ ebuf,
                                                  float* __restrict__ agg) {
    int node = blockIdx.x * 4 + (threadIdx.x >> 6);
    if (node >= N_NODES) return;
    int lane = threadIdx.x & 63;
    int half = lane >> 5, fl = lane & 31;
    int s = row_start[node], e = row_start[node + 1];
    float a0 = 0.f, a1 = 0.f, a2 = 0.f, a3 = 0.f;
    const uint2* x4 = (const uint2*)xb;              // 4 bf16 per uint2
    for (int i = s; i < e; i += 64) {
        int nloc = e - i; if (nloc > 64) nloc = 64;
        int src_l = (i + lane < e) ? ebuf[i + lane] : 0;
        int jmax = (nloc + 1) >> 1;
        for (int j = 0; j < jmax; j++) {
            int slot = 2 * j + half;
            int src = __shfl(src_l, slot, 64);
            if (slot < nloc) {
                uint2 v = x4[(size_t)src * 32 + fl];
                a0 += __uint_as_float(v.x << 16);
                a1 += __uint_as_float(v.x & 0xffff0000u);
                a2 += __uint_as_float(v.y << 16);
                a3 += __uint_as_float(v.y & 0xffff0000u);
            }
        }
    }
    float b0 = __shfl(a0, fl + 32, 64);
    float b1 = __shfl(a1, fl + 32, 64);
    float b2 = __shfl(a2, fl + 32, 64);
    float b3 = __shfl(a3, fl + 32, 64);
    if (half == 0) {
        float inv = (e > s) ? 1.0f / (float)(e - s) : 0.0f;   // deg==0 -> agg = 0
        float4 o;
        o.x = (a0 + b0) * inv; o.y = (a1 + b1) * inv;
        o.z = (a2 + b2) * inv; o.w = (a3 + b3) * inv;
        ((float4*)agg)[(size_t)node * 32 + fl] = o;
    }
}

// ---------------------------------------------------------------------------
// Fused layer GEMM: xout = relu(agg @ Wl^T + xin @ Wr^T + b)   (all fp32)
// Optionally also writes a bf16 copy of xout for the next layer's aggregation.
// Block: 256 threads, tile 32 rows x 128 cols. Thread: 4 rows x 4 cols.
// ---------------------------------------------------------------------------
__global__ __launch_bounds__(256) void sage_gemm(const float* __restrict__ agg,
                                                 const float* __restrict__ xin,
                                                 const float* __restrict__ Wl,
                                                 const float* __restrict__ Wr,
                                                 const float* __restrict__ bias,
                                                 float* __restrict__ xout,
                                                 ushort_t* __restrict__ xoutb,
                                                 int nrows) {
    __shared__ float wl_s[128][36];
    __shared__ float wr_s[128][36];
    int t = threadIdx.x;
    int r_base = blockIdx.x * 32 + (t >> 5) * 4;
    int c_lo = t & 31;
    float acc[4][4];
    #pragma unroll
    for (int r = 0; r < 4; r++)
        #pragma unroll
        for (int c = 0; c < 4; c++) acc[r][c] = 0.f;

    for (int kc = 0; kc < DIM; kc += 32) {
        __syncthreads();
        for (int i = t; i < 128 * 8; i += 256) {
            int c = i >> 3, k4 = i & 7;
            float4 wv  = ((const float4*)(Wl + c * DIM + kc))[k4];
            float4 wv2 = ((const float4*)(Wr + c * DIM + kc))[k4];
            *((float4*)&wl_s[c][k4 * 4]) = wv;
            *((float4*)&wr_s[c][k4 * 4]) = wv2;
        }
        __syncthreads();
        for (int k4 = 0; k4 < 8; k4++) {
            float4 av[4], xv[4];
            #pragma unroll
            for (int r = 0; r < 4; r++) {
                int row = r_base + r; if (row > nrows - 1) row = nrows - 1;
                av[r] = ((const float4*)(agg + (size_t)row * DIM + kc))[k4];
                xv[r] = ((const float4*)(xin + (size_t)row * DIM + kc))[k4];
            }
            #pragma unroll
            for (int cc = 0; cc < 4; cc++) {
                int c = c_lo + cc * 32;
                float4 wl4 = *((const float4*)&wl_s[c][k4 * 4]);
                float4 wr4 = *((const float4*)&wr_s[c][k4 * 4]);
                #pragma unroll
                for (int r = 0; r < 4; r++) {
                    acc[r][cc] += av[r].x * wl4.x + av[r].y * wl4.y
                                + av[r].z * wl4.z + av[r].w * wl4.w
                                + xv[r].x * wr4.x + xv[r].y * wr4.y
                                + xv[r].z * wr4.z + xv[r].w * wr4.w;
                }
            }
        }
    }
    #pragma unroll
    for (int cc = 0; cc < 4; cc++) {
        int c = c_lo + cc * 32;
        float bv = bias[c];
        #pragma unroll
        for (int r = 0; r < 4; r++) {
            int row = r_base + r;
            if (row < nrows) {
                float v = fmaxf(acc[r][cc] + bv, 0.f);
                xout[(size_t)row * DIM + c] = v;
                if (xoutb) xoutb[(size_t)row * DIM + c] = (ushort_t)bf_rne(v);
            }
        }
    }
}

// ---------------------------------------------------------------------------
// Graph boundaries from sorted batch; then fused mean-pool + FC (wave/graph).
// ---------------------------------------------------------------------------
__global__ void graph_bounds(const int* __restrict__ batch, int* __restrict__ gstart) {
    int i = blockIdx.x * 256 + threadIdx.x;
    if (i < N_NODES) {
        int b = batch[i];
        int prev = (i == 0) ? -1 : batch[i - 1];
        for (int g = prev + 1; g <= b; g++) gstart[g] = i;
        if (i == 0) {
            int last = batch[N_NODES - 1];
            for (int g = last + 1; g <= N_GRAPHS; g++) gstart[g] = N_NODES;
        }
    }
}

__global__ __launch_bounds__(256) void pool_fc(const float* __restrict__ x,
                                               const int* __restrict__ gstart,
                                               const float* __restrict__ fc_w,
                                               const float* __restrict__ fc_b,
                                               float* __restrict__ out) {
    int g = blockIdx.x * 4 + (threadIdx.x >> 6);
    if (g >= N_GRAPHS) return;
    int lane = threadIdx.x & 63;
    int s = gstart[g], e = gstart[g + 1];
    float2 acc; acc.x = 0.f; acc.y = 0.f;
    const float2* x2 = (const float2*)x;
    for (int i = s; i < e; i++) {
        float2 v = x2[(size_t)i * 64 + lane];
        acc.x += v.x; acc.y += v.y;
    }
    float inv = (e > s) ? 1.0f / (float)(e - s) : 0.0f;
    const float2* w2 = (const float2*)fc_w;
    float2 w = w2[lane];
    float sres = (acc.x * w.x + acc.y * w.y) * inv;
    for (int off = 32; off; off >>= 1) sres += __shfl_down(sres, off, 64);
    if (lane == 0) out[g] = sres + fc_b[0];
}

// ---------------------------------------------------------------------------
extern "C" void kernel_launch(void* const* d_in, const int* in_sizes, int n_in,
                              void* d_out, int out_size, void* d_ws, size_t ws_size,
                              hipStream_t stream) {
    const float* x     = (const float*)d_in[0];
    const int*   ei    = (const int*)d_in[1];
    const int*   batch = (const int*)d_in[2];
    const float* Wl[3] = {(const float*)d_in[3], (const float*)d_in[6], (const float*)d_in[9]};
    const float* bb[3] = {(const float*)d_in[4], (const float*)d_in[7], (const float*)d_in[10]};
    const float* Wr[3] = {(const float*)d_in[5], (const float*)d_in[8], (const float*)d_in[11]};
    const float* fc_w  = (const float*)d_in[12];
    const float* fc_b  = (const float*)d_in[13];
    float* out = (float*)d_out;

    char* p = (char*)d_ws;
    auto alloc = [&](size_t bytes) { char* r = p; p += (bytes + 255) & ~255ull; return r; };
    int* deg       = (int*)alloc((size_t)N_NODES * 4);
    int* cursor    = (int*)alloc((size_t)N_NODES * 4);
    int* row_start = (int*)alloc((size_t)(N_NODES + 1) * 4);
    int* bsum      = (int*)alloc((size_t)N_SBLK * 4);
    int* bofs      = (int*)alloc((size_t)N_SBLK * 4);
    int* ebuf      = (int*)alloc((size_t)N_EDGES * 4);
    int* gstart    = (int*)alloc((size_t)(N_GRAPHS + 1) * 4);
    float* agg     = (float*)alloc((size_t)N_NODES * DIM * 4);
    float* xb0     = (float*)alloc((size_t)N_NODES * DIM * 4);
    float* xb1     = (float*)alloc((size_t)N_NODES * DIM * 4);
    ushort_t* xbf0 = (ushort_t*)alloc((size_t)N_NODES * DIM * 2);
    ushort_t* xbf1 = (ushort_t*)alloc((size_t)N_NODES * DIM * 2);

    hipMemsetAsync(deg, 0, (size_t)N_NODES * 4, stream);
    hipMemsetAsync(cursor, 0, (size_t)N_NODES * 4, stream);

    hist_kernel<<<(N_EDGES + 255) / 256, 256, 0, stream>>>(ei + N_EDGES, deg);
    block_reduce<<<N_SBLK, 256, 0, stream>>>(deg, bsum);
    scan_tops<<<1, 64, 0, stream>>>(bsum, bofs);
    block_scan<<<N_SBLK, SCAN_BLOCK, 0, stream>>>(deg, bofs, row_start);
    scatter_kernel<<<(N_EDGES + 255) / 256, 256, 0, stream>>>(ei, ei + N_EDGES, row_start, cursor, ebuf);
    graph_bounds<<<(N_NODES + 255) / 256, 256, 0, stream>>>(batch, gstart);
    f32_to_bf16<<<(N_NODES * DIM / 4 + 255) / 256, 256, 0, stream>>>(x, xbf0);

    const float* xin = x;
    const ushort_t* xbin = xbf0;
    float* xout = xb0;
    ushort_t* xbout = xbf1;
    for (int l = 0; l < 3; l++) {
        agg_kernel<<<(N_NODES + 3) / 4, 256, 0, stream>>>(xbin, row_start, ebuf, agg);
        sage_gemm<<<(N_NODES + 31) / 32, 256, 0, stream>>>(agg, xin, Wl[l], Wr[l], bb[l],
                                                           xout, (l < 2) ? xbout : (ushort_t*)nullptr,
                                                           N_NODES);
        xin = xout;
        xout = (xout == xb0) ? xb1 : xb0;
        xbin = xbout;
        xbout = (xbout == xbf0) ? xbf1 : xbf0;
    }
    pool_fc<<<(N_GRAPHS + 3) / 4, 256, 0, stream>>>(xin, gstart, fc_w, fc_b, out);
}

// Round 3
// 663.145 us; speedup vs baseline: 1.3931x; 1.0751x over previous
//
#include <hip/hip_runtime.h>

#define N_NODES  50000
#define N_EDGES  1600000
#define DIM      128
#define N_GRAPHS 512
#define SCAN_BLOCK 1024
#define N_SBLK ((N_NODES + SCAN_BLOCK - 1) / SCAN_BLOCK)   // 49

typedef unsigned int uint_t;
typedef unsigned short ushort_t;
typedef __attribute__((ext_vector_type(8))) short bf16x8;
typedef __attribute__((ext_vector_type(4))) float f32x4;

__device__ inline uint_t bf_rne(float f) {   // fp32 -> bf16 bits, round-nearest-even
    uint_t u = __float_as_uint(f);
    return (u + 0x7fffu + ((u >> 16) & 1u)) >> 16;
}

// split f into hi (bf16) and lo (bf16 of residual); f ~= hi + lo to ~2^-17 rel
__device__ inline void bf_split(float f, uint_t& h, uint_t& l) {
    h = bf_rne(f);
    float hf = __uint_as_float(h << 16);
    l = bf_rne(f - hf);
}

// ---------------------------------------------------------------------------
// CSR build: histogram of dst (returning slot), hierarchical scan, scatter
// ---------------------------------------------------------------------------
__global__ void hist_kernel(const int* __restrict__ dst, int* __restrict__ deg,
                            int* __restrict__ pos) {
    int e = blockIdx.x * 256 + threadIdx.x;
    if (e < N_EDGES) pos[e] = atomicAdd(&deg[dst[e]], 1);
}

__global__ void block_reduce(const int* __restrict__ deg, int* __restrict__ bsum) {
    __shared__ int red[256];
    int b = blockIdx.x, t = threadIdx.x;
    int base = b * SCAN_BLOCK;
    int s = 0;
    for (int i = t; i < SCAN_BLOCK; i += 256) {
        int idx = base + i;
        s += (idx < N_NODES) ? deg[idx] : 0;
    }
    red[t] = s; __syncthreads();
    for (int off = 128; off; off >>= 1) {
        if (t < off) red[t] += red[t + off];
        __syncthreads();
    }
    if (t == 0) bsum[b] = red[0];
}

__global__ void scan_tops(const int* __restrict__ bsum, int* __restrict__ bofs) {
    if (threadIdx.x == 0) {
        int acc = 0;
        for (int i = 0; i < N_SBLK; i++) { bofs[i] = acc; acc += bsum[i]; }
    }
}

__global__ void block_scan(const int* __restrict__ deg, const int* __restrict__ bofs,
                           int* __restrict__ row_start) {
    __shared__ int tmp[SCAN_BLOCK];
    int b = blockIdx.x, t = threadIdx.x;
    int i = b * SCAN_BLOCK + t;
    tmp[t] = (i < N_NODES) ? deg[i] : 0;
    __syncthreads();
    for (int off = 1; off < SCAN_BLOCK; off <<= 1) {
        int add = (t >= off) ? tmp[t - off] : 0;
        __syncthreads();
        tmp[t] += add;
        __syncthreads();
    }
    if (i < N_NODES) row_start[i + 1] = tmp[t] + bofs[b];
    if (i == 0) row_start[0] = 0;
}

__global__ void scatter_kernel(const int* __restrict__ src, const int* __restrict__ dst,
                               const int* __restrict__ pos, const int* __restrict__ row_start,
                               int* __restrict__ ebuf) {
    int e = blockIdx.x * 256 + threadIdx.x;
    if (e < N_EDGES) ebuf[row_start[dst[e]] + pos[e]] = src[e];
}

// ---------------------------------------------------------------------------
// fp32 -> (hi, lo) bf16 split, x input (4 elems / thread)
// ---------------------------------------------------------------------------
__global__ void xsplit(const float* __restrict__ x, ushort_t* __restrict__ xh,
                       ushort_t* __restrict__ xl) {
    int i = blockIdx.x * 256 + threadIdx.x;
    if (i < (N_NODES * DIM) / 4) {
        float4 v = ((const float4*)x)[i];
        uint_t h0,h1,h2,h3,l0,l1,l2,l3;
        bf_split(v.x,h0,l0); bf_split(v.y,h1,l1); bf_split(v.z,h2,l2); bf_split(v.w,h3,l3);
        uint2 ho; ho.x = h0 | (h1 << 16); ho.y = h2 | (h3 << 16);
        uint2 lo; lo.x = l0 | (l1 << 16); lo.y = l2 | (l3 << 16);
        ((uint2*)xh)[i] = ho;
        ((uint2*)xl)[i] = lo;
    }
}

// Split all 6 weight matrices (order: Wl0,Wr0,Wl1,Wr1,Wl2,Wr2), 16384 elems each
__global__ void wsplit6(const float* w0, const float* w1, const float* w2,
                        const float* w3, const float* w4, const float* w5,
                        ushort_t* __restrict__ whi, ushort_t* __restrict__ wlo) {
    int i = blockIdx.x * 256 + threadIdx.x;
    if (i < 6 * 16384) {
        int ws = i >> 14, off = i & 16383;
        const float* w = (ws == 0) ? w0 : (ws == 1) ? w1 : (ws == 2) ? w2
                       : (ws == 3) ? w3 : (ws == 4) ? w4 : w5;
        uint_t h, l;
        bf_split(w[off], h, l);
        whi[i] = (ushort_t)h; wlo[i] = (ushort_t)l;
    }
}

// ---------------------------------------------------------------------------
// Mean aggregation over bf16(hi) features: one wave per node; fp32 accumulate;
// result written as hi/lo bf16 split.
// ---------------------------------------------------------------------------
__global__ __launch_bounds__(256) void agg_kernel(const ushort_t* __restrict__ xb,
                                                  const int* __restrict__ row_start,
                                                  const int* __restrict__ ebuf,
                                                  ushort_t* __restrict__ agg_hi,
                                                  ushort_t* __restrict__ agg_lo) {
    int node = blockIdx.x * 4 + (threadIdx.x >> 6);
    if (node >= N_NODES) return;
    int lane = threadIdx.x & 63;
    int half = lane >> 5, fl = lane & 31;
    int s = row_start[node], e = row_start[node + 1];
    float a0 = 0.f, a1 = 0.f, a2 = 0.f, a3 = 0.f;
    const uint2* x4 = (const uint2*)xb;              // 4 bf16 per uint2
    for (int i = s; i < e; i += 64) {
        int nloc = e - i; if (nloc > 64) nloc = 64;
        int src_l = (i + lane < e) ? ebuf[i + lane] : 0;
        int jmax = (nloc + 1) >> 1;
        for (int j = 0; j < jmax; j++) {
            int slot = 2 * j + half;
            int src = __shfl(src_l, slot, 64);
            if (slot < nloc) {
                uint2 v = x4[(size_t)src * 32 + fl];
                a0 += __uint_as_float(v.x << 16);
                a1 += __uint_as_float(v.x & 0xffff0000u);
                a2 += __uint_as_float(v.y << 16);
                a3 += __uint_as_float(v.y & 0xffff0000u);
            }
        }
    }
    float b0 = __shfl(a0, fl + 32, 64);
    float b1 = __shfl(a1, fl + 32, 64);
    float b2 = __shfl(a2, fl + 32, 64);
    float b3 = __shfl(a3, fl + 32, 64);
    if (half == 0) {
        float inv = (e > s) ? 1.0f / (float)(e - s) : 0.0f;   // deg==0 -> agg = 0
        float v0 = (a0 + b0) * inv, v1 = (a1 + b1) * inv;
        float v2 = (a2 + b2) * inv, v3 = (a3 + b3) * inv;
        uint_t h0,h1,h2,h3,l0,l1,l2,l3;
        bf_split(v0,h0,l0); bf_split(v1,h1,l1); bf_split(v2,h2,l2); bf_split(v3,h3,l3);
        uint2 ho; ho.x = h0 | (h1 << 16); ho.y = h2 | (h3 << 16);
        uint2 lo; lo.x = l0 | (l1 << 16); lo.y = l2 | (l3 << 16);
        ((uint2*)(agg_hi + (size_t)node * DIM))[fl] = ho;
        ((uint2*)(agg_lo + (size_t)node * DIM))[fl] = lo;
    }
}

// ---------------------------------------------------------------------------
// MFMA GEMM, split-bf16 fp32 emulation:
//   xout = relu(agg @ Wl^T + xin @ Wr^T + b), all operands as hi/lo bf16 pairs.
// Block 256 = 4 waves; wave handles 16 rows x 128 cols via 8 16x16 C tiles.
// A frag: lane holds A[m=lane&15][k=quad*8+j] -> 16B contiguous load.
// B frag: lane holds W[n=lane&15][k=quad*8+j] -> 16B contiguous load (B^T form).
// C/D: col=lane&15, row=quad*4+reg.
// Per (A,B) pair 3 MFMA terms: Ah*Bh + Al*Bh + Ah*Bl (drop Al*Bl, ~2^-18).
// ---------------------------------------------------------------------------
__global__ __launch_bounds__(256) void sage_gemm_mfma(
        const ushort_t* __restrict__ agg_hi, const ushort_t* __restrict__ agg_lo,
        const ushort_t* __restrict__ x_hi,   const ushort_t* __restrict__ x_lo,
        const ushort_t* __restrict__ wl_hi,  const ushort_t* __restrict__ wl_lo,
        const ushort_t* __restrict__ wr_hi,  const ushort_t* __restrict__ wr_lo,
        const float* __restrict__ bias,
        ushort_t* __restrict__ out_hi, ushort_t* __restrict__ out_lo, int nrows) {
    int wave = threadIdx.x >> 6;
    int lane = threadIdx.x & 63;
    int ml   = lane & 15;
    int quad = lane >> 4;
    int m0   = blockIdx.x * 64 + wave * 16;
    int row  = m0 + ml;
    int rowc = (row < nrows) ? row : (nrows - 1);
    size_t abase = (size_t)rowc * DIM + quad * 8;

    f32x4 acc[8];
    #pragma unroll
    for (int i = 0; i < 8; i++) acc[i] = (f32x4)0.f;

    #pragma unroll
    for (int kc = 0; kc < DIM; kc += 32) {
        bf16x8 a_ah = *(const bf16x8*)(agg_hi + abase + kc);
        bf16x8 a_al = *(const bf16x8*)(agg_lo + abase + kc);
        bf16x8 a_xh = *(const bf16x8*)(x_hi  + abase + kc);
        bf16x8 a_xl = *(const bf16x8*)(x_lo  + abase + kc);
        #pragma unroll
        for (int n0 = 0; n0 < 8; n0++) {
            size_t wo = (size_t)(n0 * 16 + ml) * DIM + kc + quad * 8;
            bf16x8 b_lh = *(const bf16x8*)(wl_hi + wo);
            bf16x8 b_ll = *(const bf16x8*)(wl_lo + wo);
            bf16x8 b_rh = *(const bf16x8*)(wr_hi + wo);
            bf16x8 b_rl = *(const bf16x8*)(wr_lo + wo);
            f32x4 c = acc[n0];
            c = __builtin_amdgcn_mfma_f32_16x16x32_bf16(a_ah, b_lh, c, 0, 0, 0);
            c = __builtin_amdgcn_mfma_f32_16x16x32_bf16(a_al, b_lh, c, 0, 0, 0);
            c = __builtin_amdgcn_mfma_f32_16x16x32_bf16(a_ah, b_ll, c, 0, 0, 0);
            c = __builtin_amdgcn_mfma_f32_16x16x32_bf16(a_xh, b_rh, c, 0, 0, 0);
            c = __builtin_amdgcn_mfma_f32_16x16x32_bf16(a_xl, b_rh, c, 0, 0, 0);
            c = __builtin_amdgcn_mfma_f32_16x16x32_bf16(a_xh, b_rl, c, 0, 0, 0);
            acc[n0] = c;
        }
    }

    #pragma unroll
    for (int n0 = 0; n0 < 8; n0++) {
        int col = n0 * 16 + ml;
        float bv = bias[col];
        #pragma unroll
        for (int r = 0; r < 4; r++) {
            int orow = m0 + quad * 4 + r;
            if (orow < nrows) {
                float v = fmaxf(acc[n0][r] + bv, 0.f);
                uint_t h, l;
                bf_split(v, h, l);
                out_hi[(size_t)orow * DIM + col] = (ushort_t)h;
                out_lo[(size_t)orow * DIM + col] = (ushort_t)l;
            }
        }
    }
}

// ---------------------------------------------------------------------------
// Graph boundaries from sorted batch; fused mean-pool + FC (wave/graph),
// features reconstructed from hi/lo.
// ---------------------------------------------------------------------------
__global__ void graph_bounds(const int* __restrict__ batch, int* __restrict__ gstart) {
    int i = blockIdx.x * 256 + threadIdx.x;
    if (i < N_NODES) {
        int b = batch[i];
        int prev = (i == 0) ? -1 : batch[i - 1];
        for (int g = prev + 1; g <= b; g++) gstart[g] = i;
        if (i == 0) {
            int last = batch[N_NODES - 1];
            for (int g = last + 1; g <= N_GRAPHS; g++) gstart[g] = N_NODES;
        }
    }
}

__global__ __launch_bounds__(256) void pool_fc(const ushort_t* __restrict__ x_hi,
                                               const ushort_t* __restrict__ x_lo,
                                               const int* __restrict__ gstart,
                                               const float* __restrict__ fc_w,
                                               const float* __restrict__ fc_b,
                                               float* __restrict__ out) {
    int g = blockIdx.x * 4 + (threadIdx.x >> 6);
    if (g >= N_GRAPHS) return;
    int lane = threadIdx.x & 63;
    int s = gstart[g], e = gstart[g + 1];
    float ax = 0.f, ay = 0.f;
    const uint_t* xh = (const uint_t*)x_hi;
    const uint_t* xl = (const uint_t*)x_lo;
    for (int i = s; i < e; i++) {
        uint_t h = xh[(size_t)i * 64 + lane];
        uint_t l = xl[(size_t)i * 64 + lane];
        ax += __uint_as_float(h << 16) + __uint_as_float(l << 16);
        ay += __uint_as_float(h & 0xffff0000u) + __uint_as_float(l & 0xffff0000u);
    }
    float inv = (e > s) ? 1.0f / (float)(e - s) : 0.0f;
    const float2* w2 = (const float2*)fc_w;
    float2 w = w2[lane];
    float sres = (ax * w.x + ay * w.y) * inv;
    for (int off = 32; off; off >>= 1) sres += __shfl_down(sres, off, 64);
    if (lane == 0) out[g] = sres + fc_b[0];
}

// ---------------------------------------------------------------------------
extern "C" void kernel_launch(void* const* d_in, const int* in_sizes, int n_in,
                              void* d_out, int out_size, void* d_ws, size_t ws_size,
                              hipStream_t stream) {
    const float* x     = (const float*)d_in[0];
    const int*   ei    = (const int*)d_in[1];
    const int*   batch = (const int*)d_in[2];
    const float* Wl[3] = {(const float*)d_in[3], (const float*)d_in[6], (const float*)d_in[9]};
    const float* bb[3] = {(const float*)d_in[4], (const float*)d_in[7], (const float*)d_in[10]};
    const float* Wr[3] = {(const float*)d_in[5], (const float*)d_in[8], (const float*)d_in[11]};
    const float* fc_w  = (const float*)d_in[12];
    const float* fc_b  = (const float*)d_in[13];
    float* out = (float*)d_out;

    char* p = (char*)d_ws;
    auto alloc = [&](size_t bytes) { char* r = p; p += (bytes + 255) & ~255ull; return r; };
    int* deg       = (int*)alloc((size_t)N_NODES * 4);
    int* row_start = (int*)alloc((size_t)(N_NODES + 1) * 4);
    int* bsum      = (int*)alloc((size_t)N_SBLK * 4);
    int* bofs      = (int*)alloc((size_t)N_SBLK * 4);
    int* pos       = (int*)alloc((size_t)N_EDGES * 4);
    int* ebuf      = (int*)alloc((size_t)N_EDGES * 4);
    int* gstart    = (int*)alloc((size_t)(N_GRAPHS + 1) * 4);
    const size_t FB = (size_t)N_NODES * DIM * 2;     // feature buffer bytes (bf16)
    ushort_t* agg_hi = (ushort_t*)alloc(FB);
    ushort_t* agg_lo = (ushort_t*)alloc(FB);
    ushort_t* fh[3]  = {(ushort_t*)alloc(FB), (ushort_t*)alloc(FB), (ushort_t*)alloc(FB)};
    ushort_t* fl_[3] = {(ushort_t*)alloc(FB), (ushort_t*)alloc(FB), (ushort_t*)alloc(FB)};
    ushort_t* whi    = (ushort_t*)alloc((size_t)6 * 16384 * 2);
    ushort_t* wlo    = (ushort_t*)alloc((size_t)6 * 16384 * 2);

    hipMemsetAsync(deg, 0, (size_t)N_NODES * 4, stream);

    hist_kernel<<<(N_EDGES + 255) / 256, 256, 0, stream>>>(ei + N_EDGES, deg, pos);
    block_reduce<<<N_SBLK, 256, 0, stream>>>(deg, bsum);
    scan_tops<<<1, 64, 0, stream>>>(bsum, bofs);
    block_scan<<<N_SBLK, SCAN_BLOCK, 0, stream>>>(deg, bofs, row_start);
    scatter_kernel<<<(N_EDGES + 255) / 256, 256, 0, stream>>>(ei, ei + N_EDGES, pos, row_start, ebuf);
    graph_bounds<<<(N_NODES + 255) / 256, 256, 0, stream>>>(batch, gstart);
    xsplit<<<(N_NODES * DIM / 4 + 255) / 256, 256, 0, stream>>>(x, fh[0], fl_[0]);
    wsplit6<<<(6 * 16384 + 255) / 256, 256, 0, stream>>>(Wl[0], Wr[0], Wl[1], Wr[1], Wl[2], Wr[2], whi, wlo);

    // buffers: layer0 in fh[0] -> out fh[1]; layer1 in fh[1] -> out fh[2]; layer2 in fh[2] -> out fh[1]
    int inb = 0;
    for (int l = 0; l < 3; l++) {
        int outb = (l == 0) ? 1 : (l == 1) ? 2 : 1;
        agg_kernel<<<(N_NODES + 3) / 4, 256, 0, stream>>>(fh[inb], row_start, ebuf, agg_hi, agg_lo);
        sage_gemm_mfma<<<(N_NODES + 63) / 64, 256, 0, stream>>>(
            agg_hi, agg_lo, fh[inb], fl_[inb],
            whi + (size_t)(2 * l) * 16384,     wlo + (size_t)(2 * l) * 16384,
            whi + (size_t)(2 * l + 1) * 16384, wlo + (size_t)(2 * l + 1) * 16384,
            bb[l], fh[outb], fl_[outb], N_NODES);
        inb = outb;
    }
    pool_fc<<<(N_GRAPHS + 3) / 4, 256, 0, stream>>>(fh[inb], fl_[inb], gstart, fc_w, fc_b, out);
}

// Round 4
// 567.522 us; speedup vs baseline: 1.6279x; 1.1685x over previous
//
#include <hip/hip_runtime.h>

#define N_NODES  50000
#define N_EDGES  1600000
#define DIM      128
#define N_GRAPHS 512
#define SCAN_BLOCK 1024
#define N_SBLK ((N_NODES + SCAN_BLOCK - 1) / SCAN_BLOCK)   // 49

typedef unsigned int uint_t;
typedef unsigned short ushort_t;
typedef __attribute__((ext_vector_type(8))) short bf16x8;
typedef __attribute__((ext_vector_type(4))) float f32x4;

__device__ inline uint_t bf_rne(float f) {   // fp32 -> bf16 bits, round-nearest-even
    uint_t u = __float_as_uint(f);
    return (u + 0x7fffu + ((u >> 16) & 1u)) >> 16;
}

// split f into hi (bf16) and lo (bf16 of residual); f ~= hi + lo to ~2^-17 rel
__device__ inline void bf_split(float f, uint_t& h, uint_t& l) {
    h = bf_rne(f);
    float hf = __uint_as_float(h << 16);
    l = bf_rne(f - hf);
}

// ---------------------------------------------------------------------------
// CSR build: histogram of dst (returning slot), hierarchical scan, scatter
// ---------------------------------------------------------------------------
__global__ void hist_kernel(const int* __restrict__ dst, int* __restrict__ deg,
                            int* __restrict__ pos) {
    int e = blockIdx.x * 256 + threadIdx.x;
    if (e < N_EDGES) pos[e] = atomicAdd(&deg[dst[e]], 1);
}

__global__ void block_reduce(const int* __restrict__ deg, int* __restrict__ bsum) {
    __shared__ int red[256];
    int b = blockIdx.x, t = threadIdx.x;
    int base = b * SCAN_BLOCK;
    int s = 0;
    for (int i = t; i < SCAN_BLOCK; i += 256) {
        int idx = base + i;
        s += (idx < N_NODES) ? deg[idx] : 0;
    }
    red[t] = s; __syncthreads();
    for (int off = 128; off; off >>= 1) {
        if (t < off) red[t] += red[t + off];
        __syncthreads();
    }
    if (t == 0) bsum[b] = red[0];
}

__global__ void scan_tops(const int* __restrict__ bsum, int* __restrict__ bofs) {
    if (threadIdx.x == 0) {
        int acc = 0;
        for (int i = 0; i < N_SBLK; i++) { bofs[i] = acc; acc += bsum[i]; }
    }
}

__global__ void block_scan(const int* __restrict__ deg, const int* __restrict__ bofs,
                           int* __restrict__ row_start) {
    __shared__ int tmp[SCAN_BLOCK];
    int b = blockIdx.x, t = threadIdx.x;
    int i = b * SCAN_BLOCK + t;
    tmp[t] = (i < N_NODES) ? deg[i] : 0;
    __syncthreads();
    for (int off = 1; off < SCAN_BLOCK; off <<= 1) {
        int add = (t >= off) ? tmp[t - off] : 0;
        __syncthreads();
        tmp[t] += add;
        __syncthreads();
    }
    if (i < N_NODES) row_start[i + 1] = tmp[t] + bofs[b];
    if (i == 0) row_start[0] = 0;
}

__global__ void scatter_kernel(const int* __restrict__ src, const int* __restrict__ dst,
                               const int* __restrict__ pos, const int* __restrict__ row_start,
                               int* __restrict__ ebuf) {
    int e = blockIdx.x * 256 + threadIdx.x;
    if (e < N_EDGES) ebuf[row_start[dst[e]] + pos[e]] = src[e];
}

// ---------------------------------------------------------------------------
// fp32 -> (hi, lo) bf16 split, x input (4 elems / thread)
// ---------------------------------------------------------------------------
__global__ void xsplit(const float* __restrict__ x, ushort_t* __restrict__ xh,
                       ushort_t* __restrict__ xl) {
    int i = blockIdx.x * 256 + threadIdx.x;
    if (i < (N_NODES * DIM) / 4) {
        float4 v = ((const float4*)x)[i];
        uint_t h0,h1,h2,h3,l0,l1,l2,l3;
        bf_split(v.x,h0,l0); bf_split(v.y,h1,l1); bf_split(v.z,h2,l2); bf_split(v.w,h3,l3);
        uint2 ho; ho.x = h0 | (h1 << 16); ho.y = h2 | (h3 << 16);
        uint2 lo; lo.x = l0 | (l1 << 16); lo.y = l2 | (l3 << 16);
        ((uint2*)xh)[i] = ho;
        ((uint2*)xl)[i] = lo;
    }
}

// Split all 6 weight matrices (order: Wl0,Wr0,Wl1,Wr1,Wl2,Wr2), 16384 elems each
__global__ void wsplit6(const float* w0, const float* w1, const float* w2,
                        const float* w3, const float* w4, const float* w5,
                        ushort_t* __restrict__ whi, ushort_t* __restrict__ wlo) {
    int i = blockIdx.x * 256 + threadIdx.x;
    if (i < 6 * 16384) {
        int ws = i >> 14, off = i & 16383;
        const float* w = (ws == 0) ? w0 : (ws == 1) ? w1 : (ws == 2) ? w2
                       : (ws == 3) ? w3 : (ws == 4) ? w4 : w5;
        uint_t h, l;
        bf_split(w[off], h, l);
        whi[i] = (ushort_t)h; wlo[i] = (ushort_t)l;
    }
}

// ---------------------------------------------------------------------------
// Mean aggregation over bf16(hi) features: one wave per node; fp32 accumulate;
// result written as hi/lo bf16 split.
// ---------------------------------------------------------------------------
__global__ __launch_bounds__(256) void agg_kernel(const ushort_t* __restrict__ xb,
                                                  const int* __restrict__ row_start,
                                                  const int* __restrict__ ebuf,
                                                  ushort_t* __restrict__ agg_hi,
                                                  ushort_t* __restrict__ agg_lo) {
    int node = blockIdx.x * 4 + (threadIdx.x >> 6);
    if (node >= N_NODES) return;
    int lane = threadIdx.x & 63;
    int half = lane >> 5, fl = lane & 31;
    int s = row_start[node], e = row_start[node + 1];
    float a0 = 0.f, a1 = 0.f, a2 = 0.f, a3 = 0.f;
    const uint2* x4 = (const uint2*)xb;              // 4 bf16 per uint2
    for (int i = s; i < e; i += 64) {
        int nloc = e - i; if (nloc > 64) nloc = 64;
        int src_l = (i + lane < e) ? ebuf[i + lane] : 0;
        int jmax = (nloc + 1) >> 1;
        for (int j = 0; j < jmax; j++) {
            int slot = 2 * j + half;
            int src = __shfl(src_l, slot, 64);
            if (slot < nloc) {
                uint2 v = x4[(size_t)src * 32 + fl];
                a0 += __uint_as_float(v.x << 16);
                a1 += __uint_as_float(v.x & 0xffff0000u);
                a2 += __uint_as_float(v.y << 16);
                a3 += __uint_as_float(v.y & 0xffff0000u);
            }
        }
    }
    float b0 = __shfl(a0, fl + 32, 64);
    float b1 = __shfl(a1, fl + 32, 64);
    float b2 = __shfl(a2, fl + 32, 64);
    float b3 = __shfl(a3, fl + 32, 64);
    if (half == 0) {
        float inv = (e > s) ? 1.0f / (float)(e - s) : 0.0f;   // deg==0 -> agg = 0
        float v0 = (a0 + b0) * inv, v1 = (a1 + b1) * inv;
        float v2 = (a2 + b2) * inv, v3 = (a3 + b3) * inv;
        uint_t h0,h1,h2,h3,l0,l1,l2,l3;
        bf_split(v0,h0,l0); bf_split(v1,h1,l1); bf_split(v2,h2,l2); bf_split(v3,h3,l3);
        uint2 ho; ho.x = h0 | (h1 << 16); ho.y = h2 | (h3 << 16);
        uint2 lo; lo.x = l0 | (l1 << 16); lo.y = l2 | (l3 << 16);
        ((uint2*)(agg_hi + (size_t)node * DIM))[fl] = ho;
        ((uint2*)(agg_lo + (size_t)node * DIM))[fl] = lo;
    }
}

// ---------------------------------------------------------------------------
// MFMA GEMM, split-bf16 fp32 emulation with LDS-staged hi-weights.
//   xout = relu(agg @ Wl^T + xin @ Wr^T + b)
// Block 256 = 4 waves; each wave 4 row-tiles (64 rows) -> 256 rows/block.
// Hi-weights (Wl_hi, Wr_hi) staged in LDS (64 KB) with XOR chunk swizzle:
//   chunk ch (16 B) of row r stored at position ch^(r&7) -> even bank spread
//   for ds_read_b128 fragment reads. Lo-weights read from global (L2-hot);
//   their latency hides under 24 MFMAs per (kc,n0).
// Fragment maps (verified r2): A lane holds M[m=lane&15][k=quad*8+j];
// C/D col=lane&15, row=quad*4+reg.
// ---------------------------------------------------------------------------
__global__ __launch_bounds__(256, 1) void sage_gemm_mfma(
        const ushort_t* __restrict__ agg_hi, const ushort_t* __restrict__ agg_lo,
        const ushort_t* __restrict__ x_hi,   const ushort_t* __restrict__ x_lo,
        const ushort_t* __restrict__ wl_hi,  const ushort_t* __restrict__ wl_lo,
        const ushort_t* __restrict__ wr_hi,  const ushort_t* __restrict__ wr_lo,
        const float* __restrict__ bias,
        ushort_t* __restrict__ out_hi, ushort_t* __restrict__ out_lo, int nrows) {
    __shared__ ushort_t whi_s[2][16384];    // 64 KB: [0]=Wl_hi, [1]=Wr_hi (swizzled)
    int t = threadIdx.x;
    for (int i = t; i < 4096; i += 256) {   // 2 arrays x 128 rows x 16 chunks
        int a = i >> 11, rem = i & 2047, row = rem >> 4, ch = rem & 15;
        int sw = ch ^ (row & 7);
        const ushort_t* srcp = a ? wr_hi : wl_hi;
        uint4 v = *(const uint4*)(srcp + row * DIM + ch * 8);
        *(uint4*)((char*)&whi_s[a][0] + row * 256 + sw * 16) = v;
    }
    __syncthreads();

    int wave = t >> 6, lane = t & 63;
    int ml = lane & 15, quad = lane >> 4;
    int m0 = blockIdx.x * 256 + wave * 64;

    f32x4 acc[8][4];
    #pragma unroll
    for (int n0 = 0; n0 < 8; n0++)
        #pragma unroll
        for (int rt = 0; rt < 4; rt++) acc[n0][rt] = (f32x4)0.f;

    size_t abase[4];
    #pragma unroll
    for (int rt = 0; rt < 4; rt++) {
        int row = m0 + rt * 16 + ml;
        int rowc = (row < nrows) ? row : (nrows - 1);
        abase[rt] = (size_t)rowc * DIM + quad * 8;
    }

    #pragma unroll
    for (int kc = 0; kc < DIM; kc += 32) {
        bf16x8 Aah[4], Aal[4], Axh[4], Axl[4];
        #pragma unroll
        for (int rt = 0; rt < 4; rt++) {
            Aah[rt] = *(const bf16x8*)(agg_hi + abase[rt] + kc);
            Aal[rt] = *(const bf16x8*)(agg_lo + abase[rt] + kc);
            Axh[rt] = *(const bf16x8*)(x_hi   + abase[rt] + kc);
            Axl[rt] = *(const bf16x8*)(x_lo   + abase[rt] + kc);
        }
        int kch = (kc >> 3) + quad;          // 16B-chunk index within row
        int sw16 = (kch ^ (ml & 7)) * 16;
        #pragma unroll
        for (int n0 = 0; n0 < 8; n0++) {
            int nrow = n0 * 16 + ml;
            bf16x8 b_lh = *(const bf16x8*)((const char*)&whi_s[0][0] + nrow * 256 + sw16);
            bf16x8 b_rh = *(const bf16x8*)((const char*)&whi_s[1][0] + nrow * 256 + sw16);
            size_t wo = (size_t)nrow * DIM + kc + quad * 8;
            bf16x8 b_ll = *(const bf16x8*)(wl_lo + wo);
            bf16x8 b_rl = *(const bf16x8*)(wr_lo + wo);
            #pragma unroll
            for (int rt = 0; rt < 4; rt++) {
                f32x4 c = acc[n0][rt];
                c = __builtin_amdgcn_mfma_f32_16x16x32_bf16(Aah[rt], b_lh, c, 0, 0, 0);
                c = __builtin_amdgcn_mfma_f32_16x16x32_bf16(Aal[rt], b_lh, c, 0, 0, 0);
                c = __builtin_amdgcn_mfma_f32_16x16x32_bf16(Aah[rt], b_ll, c, 0, 0, 0);
                c = __builtin_amdgcn_mfma_f32_16x16x32_bf16(Axh[rt], b_rh, c, 0, 0, 0);
                c = __builtin_amdgcn_mfma_f32_16x16x32_bf16(Axl[rt], b_rh, c, 0, 0, 0);
                c = __builtin_amdgcn_mfma_f32_16x16x32_bf16(Axh[rt], b_rl, c, 0, 0, 0);
                acc[n0][rt] = c;
            }
        }
    }

    #pragma unroll
    for (int n0 = 0; n0 < 8; n0++) {
        int col = n0 * 16 + ml;
        float bv = bias[col];
        #pragma unroll
        for (int rt = 0; rt < 4; rt++) {
            #pragma unroll
            for (int r = 0; r < 4; r++) {
                int orow = m0 + rt * 16 + quad * 4 + r;
                if (orow < nrows) {
                    float v = fmaxf(acc[n0][rt][r] + bv, 0.f);
                    uint_t h, l;
                    bf_split(v, h, l);
                    out_hi[(size_t)orow * DIM + col] = (ushort_t)h;
                    out_lo[(size_t)orow * DIM + col] = (ushort_t)l;
                }
            }
        }
    }
}

// ---------------------------------------------------------------------------
// Graph boundaries from sorted batch; fused mean-pool + FC (wave/graph),
// features reconstructed from hi/lo.
// ---------------------------------------------------------------------------
__global__ void graph_bounds(const int* __restrict__ batch, int* __restrict__ gstart) {
    int i = blockIdx.x * 256 + threadIdx.x;
    if (i < N_NODES) {
        int b = batch[i];
        int prev = (i == 0) ? -1 : batch[i - 1];
        for (int g = prev + 1; g <= b; g++) gstart[g] = i;
        if (i == 0) {
            int last = batch[N_NODES - 1];
            for (int g = last + 1; g <= N_GRAPHS; g++) gstart[g] = N_NODES;
        }
    }
}

__global__ __launch_bounds__(256) void pool_fc(const ushort_t* __restrict__ x_hi,
                                               const ushort_t* __restrict__ x_lo,
                                               const int* __restrict__ gstart,
                                               const float* __restrict__ fc_w,
                                               const float* __restrict__ fc_b,
                                               float* __restrict__ out) {
    int g = blockIdx.x * 4 + (threadIdx.x >> 6);
    if (g >= N_GRAPHS) return;
    int lane = threadIdx.x & 63;
    int s = gstart[g], e = gstart[g + 1];
    float ax = 0.f, ay = 0.f;
    const uint_t* xh = (const uint_t*)x_hi;
    const uint_t* xl = (const uint_t*)x_lo;
    for (int i = s; i < e; i++) {
        uint_t h = xh[(size_t)i * 64 + lane];
        uint_t l = xl[(size_t)i * 64 + lane];
        ax += __uint_as_float(h << 16) + __uint_as_float(l << 16);
        ay += __uint_as_float(h & 0xffff0000u) + __uint_as_float(l & 0xffff0000u);
    }
    float inv = (e > s) ? 1.0f / (float)(e - s) : 0.0f;
    const float2* w2 = (const float2*)fc_w;
    float2 w = w2[lane];
    float sres = (ax * w.x + ay * w.y) * inv;
    for (int off = 32; off; off >>= 1) sres += __shfl_down(sres, off, 64);
    if (lane == 0) out[g] = sres + fc_b[0];
}

// ---------------------------------------------------------------------------
extern "C" void kernel_launch(void* const* d_in, const int* in_sizes, int n_in,
                              void* d_out, int out_size, void* d_ws, size_t ws_size,
                              hipStream_t stream) {
    const float* x     = (const float*)d_in[0];
    const int*   ei    = (const int*)d_in[1];
    const int*   batch = (const int*)d_in[2];
    const float* Wl[3] = {(const float*)d_in[3], (const float*)d_in[6], (const float*)d_in[9]};
    const float* bb[3] = {(const float*)d_in[4], (const float*)d_in[7], (const float*)d_in[10]};
    const float* Wr[3] = {(const float*)d_in[5], (const float*)d_in[8], (const float*)d_in[11]};
    const float* fc_w  = (const float*)d_in[12];
    const float* fc_b  = (const float*)d_in[13];
    float* out = (float*)d_out;

    char* p = (char*)d_ws;
    auto alloc = [&](size_t bytes) { char* r = p; p += (bytes + 255) & ~255ull; return r; };
    int* deg       = (int*)alloc((size_t)N_NODES * 4);
    int* row_start = (int*)alloc((size_t)(N_NODES + 1) * 4);
    int* bsum      = (int*)alloc((size_t)N_SBLK * 4);
    int* bofs      = (int*)alloc((size_t)N_SBLK * 4);
    int* pos       = (int*)alloc((size_t)N_EDGES * 4);
    int* ebuf      = (int*)alloc((size_t)N_EDGES * 4);
    int* gstart    = (int*)alloc((size_t)(N_GRAPHS + 1) * 4);
    const size_t FB = (size_t)N_NODES * DIM * 2;     // feature buffer bytes (bf16)
    ushort_t* agg_hi = (ushort_t*)alloc(FB);
    ushort_t* agg_lo = (ushort_t*)alloc(FB);
    ushort_t* fh[3]  = {(ushort_t*)alloc(FB), (ushort_t*)alloc(FB), (ushort_t*)alloc(FB)};
    ushort_t* fl_[3] = {(ushort_t*)alloc(FB), (ushort_t*)alloc(FB), (ushort_t*)alloc(FB)};
    ushort_t* whi    = (ushort_t*)alloc((size_t)6 * 16384 * 2);
    ushort_t* wlo    = (ushort_t*)alloc((size_t)6 * 16384 * 2);

    hipMemsetAsync(deg, 0, (size_t)N_NODES * 4, stream);

    hist_kernel<<<(N_EDGES + 255) / 256, 256, 0, stream>>>(ei + N_EDGES, deg, pos);
    block_reduce<<<N_SBLK, 256, 0, stream>>>(deg, bsum);
    scan_tops<<<1, 64, 0, stream>>>(bsum, bofs);
    block_scan<<<N_SBLK, SCAN_BLOCK, 0, stream>>>(deg, bofs, row_start);
    scatter_kernel<<<(N_EDGES + 255) / 256, 256, 0, stream>>>(ei, ei + N_EDGES, pos, row_start, ebuf);
    graph_bounds<<<(N_NODES + 255) / 256, 256, 0, stream>>>(batch, gstart);
    xsplit<<<(N_NODES * DIM / 4 + 255) / 256, 256, 0, stream>>>(x, fh[0], fl_[0]);
    wsplit6<<<(6 * 16384 + 255) / 256, 256, 0, stream>>>(Wl[0], Wr[0], Wl[1], Wr[1], Wl[2], Wr[2], whi, wlo);

    // buffers: layer0 in fh[0] -> out fh[1]; layer1 in fh[1] -> out fh[2]; layer2 in fh[2] -> out fh[1]
    int inb = 0;
    for (int l = 0; l < 3; l++) {
        int outb = (l == 0) ? 1 : (l == 1) ? 2 : 1;
        agg_kernel<<<(N_NODES + 3) / 4, 256, 0, stream>>>(fh[inb], row_start, ebuf, agg_hi, agg_lo);
        sage_gemm_mfma<<<(N_NODES + 255) / 256, 256, 0, stream>>>(
            agg_hi, agg_lo, fh[inb], fl_[inb],
            whi + (size_t)(2 * l) * 16384,     wlo + (size_t)(2 * l) * 16384,
            whi + (size_t)(2 * l + 1) * 16384, wlo + (size_t)(2 * l + 1) * 16384,
            bb[l], fh[outb], fl_[outb], N_NODES);
        inb = outb;
    }
    pool_fc<<<(N_GRAPHS + 3) / 4, 256, 0, stream>>>(fh[inb], fl_[inb], gstart, fc_w, fc_b, out);
}

// Round 5
// 541.057 us; speedup vs baseline: 1.7075x; 1.0489x over previous
//
#include <hip/hip_runtime.h>

#define N_NODES  50000
#define N_EDGES  1600000
#define DIM      128
#define N_GRAPHS 512
#define SCAN_BLOCK 1024
#define N_SBLK ((N_NODES + SCAN_BLOCK - 1) / SCAN_BLOCK)   // 49

typedef unsigned int uint_t;
typedef unsigned short ushort_t;
typedef __attribute__((ext_vector_type(8))) short bf16x8;
typedef __attribute__((ext_vector_type(4))) float f32x4;

__device__ inline uint_t bf_rne(float f) {   // fp32 -> bf16 bits, round-nearest-even
    uint_t u = __float_as_uint(f);
    return (u + 0x7fffu + ((u >> 16) & 1u)) >> 16;
}

// split f into hi (bf16) and lo (bf16 of residual); f ~= hi + lo to ~2^-17 rel
__device__ inline void bf_split(float f, uint_t& h, uint_t& l) {
    h = bf_rne(f);
    float hf = __uint_as_float(h << 16);
    l = bf_rne(f - hf);
}

// ---------------------------------------------------------------------------
// CSR build: histogram of dst (returning slot), hierarchical scan, scatter
// ---------------------------------------------------------------------------
__global__ void hist_kernel(const int* __restrict__ dst, int* __restrict__ deg,
                            int* __restrict__ pos) {
    int e = blockIdx.x * 256 + threadIdx.x;
    if (e < N_EDGES) pos[e] = atomicAdd(&deg[dst[e]], 1);
}

__global__ void block_reduce(const int* __restrict__ deg, int* __restrict__ bsum) {
    __shared__ int red[256];
    int b = blockIdx.x, t = threadIdx.x;
    int base = b * SCAN_BLOCK;
    int s = 0;
    for (int i = t; i < SCAN_BLOCK; i += 256) {
        int idx = base + i;
        s += (idx < N_NODES) ? deg[idx] : 0;
    }
    red[t] = s; __syncthreads();
    for (int off = 128; off; off >>= 1) {
        if (t < off) red[t] += red[t + off];
        __syncthreads();
    }
    if (t == 0) bsum[b] = red[0];
}

__global__ void scan_tops(const int* __restrict__ bsum, int* __restrict__ bofs) {
    if (threadIdx.x == 0) {
        int acc = 0;
        for (int i = 0; i < N_SBLK; i++) { bofs[i] = acc; acc += bsum[i]; }
    }
}

__global__ void block_scan(const int* __restrict__ deg, const int* __restrict__ bofs,
                           int* __restrict__ row_start) {
    __shared__ int tmp[SCAN_BLOCK];
    int b = blockIdx.x, t = threadIdx.x;
    int i = b * SCAN_BLOCK + t;
    tmp[t] = (i < N_NODES) ? deg[i] : 0;
    __syncthreads();
    for (int off = 1; off < SCAN_BLOCK; off <<= 1) {
        int add = (t >= off) ? tmp[t - off] : 0;
        __syncthreads();
        tmp[t] += add;
        __syncthreads();
    }
    if (i < N_NODES) row_start[i + 1] = tmp[t] + bofs[b];
    if (i == 0) row_start[0] = 0;
}

__global__ void scatter_kernel(const int* __restrict__ src, const int* __restrict__ dst,
                               const int* __restrict__ pos, const int* __restrict__ row_start,
                               int* __restrict__ ebuf) {
    int e = blockIdx.x * 256 + threadIdx.x;
    if (e < N_EDGES) ebuf[row_start[dst[e]] + pos[e]] = src[e];
}

// ---------------------------------------------------------------------------
// fp32 -> (hi, lo) bf16 split, x input (4 elems / thread)
// ---------------------------------------------------------------------------
__global__ void xsplit(const float* __restrict__ x, ushort_t* __restrict__ xh,
                       ushort_t* __restrict__ xl) {
    int i = blockIdx.x * 256 + threadIdx.x;
    if (i < (N_NODES * DIM) / 4) {
        float4 v = ((const float4*)x)[i];
        uint_t h0,h1,h2,h3,l0,l1,l2,l3;
        bf_split(v.x,h0,l0); bf_split(v.y,h1,l1); bf_split(v.z,h2,l2); bf_split(v.w,h3,l3);
        uint2 ho; ho.x = h0 | (h1 << 16); ho.y = h2 | (h3 << 16);
        uint2 lo; lo.x = l0 | (l1 << 16); lo.y = l2 | (l3 << 16);
        ((uint2*)xh)[i] = ho;
        ((uint2*)xl)[i] = lo;
    }
}

// bf16-hi only for all 6 weight matrices (order: Wl0,Wr0,Wl1,Wr1,Wl2,Wr2)
__global__ void wsplit6(const float* w0, const float* w1, const float* w2,
                        const float* w3, const float* w4, const float* w5,
                        ushort_t* __restrict__ whi) {
    int i = blockIdx.x * 256 + threadIdx.x;
    if (i < 6 * 16384) {
        int ws = i >> 14, off = i & 16383;
        const float* w = (ws == 0) ? w0 : (ws == 1) ? w1 : (ws == 2) ? w2
                       : (ws == 3) ? w3 : (ws == 4) ? w4 : w5;
        whi[i] = (ushort_t)bf_rne(w[off]);
    }
}

// ---------------------------------------------------------------------------
// Mean aggregation over bf16(hi) features: one wave per node; fp32 accumulate;
// result written as hi/lo bf16 split.
// ---------------------------------------------------------------------------
__global__ __launch_bounds__(256) void agg_kernel(const ushort_t* __restrict__ xb,
                                                  const int* __restrict__ row_start,
                                                  const int* __restrict__ ebuf,
                                                  ushort_t* __restrict__ agg_hi,
                                                  ushort_t* __restrict__ agg_lo) {
    int node = blockIdx.x * 4 + (threadIdx.x >> 6);
    if (node >= N_NODES) return;
    int lane = threadIdx.x & 63;
    int half = lane >> 5, fl = lane & 31;
    int s = row_start[node], e = row_start[node + 1];
    float a0 = 0.f, a1 = 0.f, a2 = 0.f, a3 = 0.f;
    const uint2* x4 = (const uint2*)xb;              // 4 bf16 per uint2
    for (int i = s; i < e; i += 64) {
        int nloc = e - i; if (nloc > 64) nloc = 64;
        int src_l = (i + lane < e) ? ebuf[i + lane] : 0;
        int jmax = (nloc + 1) >> 1;
        for (int j = 0; j < jmax; j++) {
            int slot = 2 * j + half;
            int src = __shfl(src_l, slot, 64);
            if (slot < nloc) {
                uint2 v = x4[(size_t)src * 32 + fl];
                a0 += __uint_as_float(v.x << 16);
                a1 += __uint_as_float(v.x & 0xffff0000u);
                a2 += __uint_as_float(v.y << 16);
                a3 += __uint_as_float(v.y & 0xffff0000u);
            }
        }
    }
    float b0 = __shfl(a0, fl + 32, 64);
    float b1 = __shfl(a1, fl + 32, 64);
    float b2 = __shfl(a2, fl + 32, 64);
    float b3 = __shfl(a3, fl + 32, 64);
    if (half == 0) {
        float inv = (e > s) ? 1.0f / (float)(e - s) : 0.0f;   // deg==0 -> agg = 0
        float v0 = (a0 + b0) * inv, v1 = (a1 + b1) * inv;
        float v2 = (a2 + b2) * inv, v3 = (a3 + b3) * inv;
        uint_t h0,h1,h2,h3,l0,l1,l2,l3;
        bf_split(v0,h0,l0); bf_split(v1,h1,l1); bf_split(v2,h2,l2); bf_split(v3,h3,l3);
        uint2 ho; ho.x = h0 | (h1 << 16); ho.y = h2 | (h3 << 16);
        uint2 lo; lo.x = l0 | (l1 << 16); lo.y = l2 | (l3 << 16);
        ((uint2*)(agg_hi + (size_t)node * DIM))[fl] = ho;
        ((uint2*)(agg_lo + (size_t)node * DIM))[fl] = lo;
    }
}

// ---------------------------------------------------------------------------
// MFMA GEMM: xout = relu(agg @ Wl^T + x @ Wr^T + b)
// A-side split-bf16 (hi+lo), weights bf16-hi only (4 MFMA terms/tile).
// Block 256 = 4 waves x 16 rows = 64 rows/block; grid 782 -> ~3 blocks/CU of
// work, 2 co-resident (LDS 64KB). Inner loop: 2 ds_read_b128 + 4 MFMA per
// n0-tile, no global loads -> 8 independent acc chains.
// LDS XOR chunk swizzle: chunk ch of row r at ch^(r&7) -> 2-way max on
// ds_read_b128 fragment reads.
// Fragment maps (verified r2): A lane holds M[m=lane&15][k=quad*8+j];
// C/D col=lane&15, row=quad*4+reg.
// ---------------------------------------------------------------------------
__global__ __launch_bounds__(256, 2) void sage_gemm_mfma(
        const ushort_t* __restrict__ agg_hi, const ushort_t* __restrict__ agg_lo,
        const ushort_t* __restrict__ x_hi,   const ushort_t* __restrict__ x_lo,
        const ushort_t* __restrict__ wl_hi,  const ushort_t* __restrict__ wr_hi,
        const float* __restrict__ bias,
        ushort_t* __restrict__ out_hi, ushort_t* __restrict__ out_lo, int nrows) {
    __shared__ ushort_t whi_s[2][16384];    // 64 KB: [0]=Wl_hi, [1]=Wr_hi (swizzled)
    int t = threadIdx.x;
    for (int i = t; i < 4096; i += 256) {   // 2 arrays x 128 rows x 16 chunks
        int a = i >> 11, rem = i & 2047, row = rem >> 4, ch = rem & 15;
        int sw = ch ^ (row & 7);
        const ushort_t* srcp = a ? wr_hi : wl_hi;
        uint4 v = *(const uint4*)(srcp + row * DIM + ch * 8);
        *(uint4*)((char*)&whi_s[a][0] + row * 256 + sw * 16) = v;
    }
    __syncthreads();

    int wave = t >> 6, lane = t & 63;
    int ml = lane & 15, quad = lane >> 4;
    int m0 = blockIdx.x * 64 + wave * 16;
    int row = m0 + ml;
    int rowc = (row < nrows) ? row : (nrows - 1);
    size_t abase = (size_t)rowc * DIM + quad * 8;

    f32x4 acc[8];
    #pragma unroll
    for (int i = 0; i < 8; i++) acc[i] = (f32x4)0.f;

    #pragma unroll
    for (int kc = 0; kc < DIM; kc += 32) {
        bf16x8 Aah = *(const bf16x8*)(agg_hi + abase + kc);
        bf16x8 Aal = *(const bf16x8*)(agg_lo + abase + kc);
        bf16x8 Axh = *(const bf16x8*)(x_hi   + abase + kc);
        bf16x8 Axl = *(const bf16x8*)(x_lo   + abase + kc);
        int kch = (kc >> 3) + quad;          // 16B-chunk index within row
        int sw16 = (kch ^ (ml & 7)) * 16;    // nrow&7 == ml&7 (n0*16 ≡ 0 mod 8)
        #pragma unroll
        for (int n0 = 0; n0 < 8; n0++) {
            int nrow = n0 * 16 + ml;
            bf16x8 b_lh = *(const bf16x8*)((const char*)&whi_s[0][0] + nrow * 256 + sw16);
            bf16x8 b_rh = *(const bf16x8*)((const char*)&whi_s[1][0] + nrow * 256 + sw16);
            f32x4 c = acc[n0];
            c = __builtin_amdgcn_mfma_f32_16x16x32_bf16(Aah, b_lh, c, 0, 0, 0);
            c = __builtin_amdgcn_mfma_f32_16x16x32_bf16(Aal, b_lh, c, 0, 0, 0);
            c = __builtin_amdgcn_mfma_f32_16x16x32_bf16(Axh, b_rh, c, 0, 0, 0);
            c = __builtin_amdgcn_mfma_f32_16x16x32_bf16(Axl, b_rh, c, 0, 0, 0);
            acc[n0] = c;
        }
    }

    #pragma unroll
    for (int n0 = 0; n0 < 8; n0++) {
        int col = n0 * 16 + ml;
        float bv = bias[col];
        #pragma unroll
        for (int r = 0; r < 4; r++) {
            int orow = m0 + quad * 4 + r;
            if (orow < nrows) {
                float v = fmaxf(acc[n0][r] + bv, 0.f);
                uint_t h, l;
                bf_split(v, h, l);
                out_hi[(size_t)orow * DIM + col] = (ushort_t)h;
                out_lo[(size_t)orow * DIM + col] = (ushort_t)l;
            }
        }
    }
}

// ---------------------------------------------------------------------------
// Graph boundaries from sorted batch; fused mean-pool + FC (wave/graph),
// features reconstructed from hi/lo.
// ---------------------------------------------------------------------------
__global__ void graph_bounds(const int* __restrict__ batch, int* __restrict__ gstart) {
    int i = blockIdx.x * 256 + threadIdx.x;
    if (i < N_NODES) {
        int b = batch[i];
        int prev = (i == 0) ? -1 : batch[i - 1];
        for (int g = prev + 1; g <= b; g++) gstart[g] = i;
        if (i == 0) {
            int last = batch[N_NODES - 1];
            for (int g = last + 1; g <= N_GRAPHS; g++) gstart[g] = N_NODES;
        }
    }
}

__global__ __launch_bounds__(256) void pool_fc(const ushort_t* __restrict__ x_hi,
                                               const ushort_t* __restrict__ x_lo,
                                               const int* __restrict__ gstart,
                                               const float* __restrict__ fc_w,
                                               const float* __restrict__ fc_b,
                                               float* __restrict__ out) {
    int g = blockIdx.x * 4 + (threadIdx.x >> 6);
    if (g >= N_GRAPHS) return;
    int lane = threadIdx.x & 63;
    int s = gstart[g], e = gstart[g + 1];
    float ax = 0.f, ay = 0.f;
    const uint_t* xh = (const uint_t*)x_hi;
    const uint_t* xl = (const uint_t*)x_lo;
    for (int i = s; i < e; i++) {
        uint_t h = xh[(size_t)i * 64 + lane];
        uint_t l = xl[(size_t)i * 64 + lane];
        ax += __uint_as_float(h << 16) + __uint_as_float(l << 16);
        ay += __uint_as_float(h & 0xffff0000u) + __uint_as_float(l & 0xffff0000u);
    }
    float inv = (e > s) ? 1.0f / (float)(e - s) : 0.0f;
    const float2* w2 = (const float2*)fc_w;
    float2 w = w2[lane];
    float sres = (ax * w.x + ay * w.y) * inv;
    for (int off = 32; off; off >>= 1) sres += __shfl_down(sres, off, 64);
    if (lane == 0) out[g] = sres + fc_b[0];
}

// ---------------------------------------------------------------------------
extern "C" void kernel_launch(void* const* d_in, const int* in_sizes, int n_in,
                              void* d_out, int out_size, void* d_ws, size_t ws_size,
                              hipStream_t stream) {
    const float* x     = (const float*)d_in[0];
    const int*   ei    = (const int*)d_in[1];
    const int*   batch = (const int*)d_in[2];
    const float* Wl[3] = {(const float*)d_in[3], (const float*)d_in[6], (const float*)d_in[9]};
    const float* bb[3] = {(const float*)d_in[4], (const float*)d_in[7], (const float*)d_in[10]};
    const float* Wr[3] = {(const float*)d_in[5], (const float*)d_in[8], (const float*)d_in[11]};
    const float* fc_w  = (const float*)d_in[12];
    const float* fc_b  = (const float*)d_in[13];
    float* out = (float*)d_out;

    char* p = (char*)d_ws;
    auto alloc = [&](size_t bytes) { char* r = p; p += (bytes + 255) & ~255ull; return r; };
    int* deg       = (int*)alloc((size_t)N_NODES * 4);
    int* row_start = (int*)alloc((size_t)(N_NODES + 1) * 4);
    int* bsum      = (int*)alloc((size_t)N_SBLK * 4);
    int* bofs      = (int*)alloc((size_t)N_SBLK * 4);
    int* pos       = (int*)alloc((size_t)N_EDGES * 4);
    int* ebuf      = (int*)alloc((size_t)N_EDGES * 4);
    int* gstart    = (int*)alloc((size_t)(N_GRAPHS + 1) * 4);
    const size_t FB = (size_t)N_NODES * DIM * 2;     // feature buffer bytes (bf16)
    ushort_t* agg_hi = (ushort_t*)alloc(FB);
    ushort_t* agg_lo = (ushort_t*)alloc(FB);
    ushort_t* fh[3]  = {(ushort_t*)alloc(FB), (ushort_t*)alloc(FB), (ushort_t*)alloc(FB)};
    ushort_t* fl_[3] = {(ushort_t*)alloc(FB), (ushort_t*)alloc(FB), (ushort_t*)alloc(FB)};
    ushort_t* whi    = (ushort_t*)alloc((size_t)6 * 16384 * 2);

    hipMemsetAsync(deg, 0, (size_t)N_NODES * 4, stream);

    hist_kernel<<<(N_EDGES + 255) / 256, 256, 0, stream>>>(ei + N_EDGES, deg, pos);
    block_reduce<<<N_SBLK, 256, 0, stream>>>(deg, bsum);
    scan_tops<<<1, 64, 0, stream>>>(bsum, bofs);
    block_scan<<<N_SBLK, SCAN_BLOCK, 0, stream>>>(deg, bofs, row_start);
    scatter_kernel<<<(N_EDGES + 255) / 256, 256, 0, stream>>>(ei, ei + N_EDGES, pos, row_start, ebuf);
    graph_bounds<<<(N_NODES + 255) / 256, 256, 0, stream>>>(batch, gstart);
    xsplit<<<(N_NODES * DIM / 4 + 255) / 256, 256, 0, stream>>>(x, fh[0], fl_[0]);
    wsplit6<<<(6 * 16384 + 255) / 256, 256, 0, stream>>>(Wl[0], Wr[0], Wl[1], Wr[1], Wl[2], Wr[2], whi);

    // buffers: layer0 in fh[0] -> out fh[1]; layer1 in fh[1] -> out fh[2]; layer2 in fh[2] -> out fh[1]
    int inb = 0;
    for (int l = 0; l < 3; l++) {
        int outb = (l == 0) ? 1 : (l == 1) ? 2 : 1;
        agg_kernel<<<(N_NODES + 3) / 4, 256, 0, stream>>>(fh[inb], row_start, ebuf, agg_hi, agg_lo);
        sage_gemm_mfma<<<(N_NODES + 63) / 64, 256, 0, stream>>>(
            agg_hi, agg_lo, fh[inb], fl_[inb],
            whi + (size_t)(2 * l) * 16384, whi + (size_t)(2 * l + 1) * 16384,
            bb[l], fh[outb], fl_[outb], N_NODES);
        inb = outb;
    }
    pool_fc<<<(N_GRAPHS + 3) / 4, 256, 0, stream>>>(fh[inb], fl_[inb], gstart, fc_w, fc_b, out);
}

// Round 6
// 495.956 us; speedup vs baseline: 1.8628x; 1.0909x over previous
//
#include <hip/hip_runtime.h>

#define N_NODES  50000
#define N_EDGES  1600000
#define DIM      128
#define N_GRAPHS 512
#define SCAN_BLOCK 1024
#define N_SBLK ((N_NODES + SCAN_BLOCK - 1) / SCAN_BLOCK)   // 49
#define NSHARD 8

typedef unsigned int uint_t;
typedef unsigned short ushort_t;
typedef __attribute__((ext_vector_type(8))) short bf16x8;
typedef __attribute__((ext_vector_type(4))) float f32x4;

__device__ inline uint_t bf_rne(float f) {   // fp32 -> bf16 bits, round-nearest-even
    uint_t u = __float_as_uint(f);
    return (u + 0x7fffu + ((u >> 16) & 1u)) >> 16;
}

// split f into hi (bf16) and lo (bf16 of residual); f ~= hi + lo to ~2^-17 rel
__device__ inline void bf_split(float f, uint_t& h, uint_t& l) {
    h = bf_rne(f);
    float hf = __uint_as_float(h << 16);
    l = bf_rne(f - hf);
}

// ---------------------------------------------------------------------------
// CSR build: sharded histogram (8 copies, shard = blockIdx&7 -> ~XCD-local,
// 8x fewer same-address collisions), combine, scan, scatter.
// ---------------------------------------------------------------------------
__global__ void hist_kernel(const int* __restrict__ dst, int* __restrict__ deg_sh,
                            int* __restrict__ pos) {
    int e = blockIdx.x * 256 + threadIdx.x;
    if (e < N_EDGES) {
        int shard = blockIdx.x & (NSHARD - 1);
        pos[e] = atomicAdd(&deg_sh[shard * N_NODES + dst[e]], 1);
    }
}

__global__ void combine_shards(const int* __restrict__ deg_sh, int* __restrict__ deg,
                               int* __restrict__ shard_ofs) {
    int n = blockIdx.x * 256 + threadIdx.x;
    if (n < N_NODES) {
        int acc = 0;
        #pragma unroll
        for (int k = 0; k < NSHARD; k++) {
            shard_ofs[k * N_NODES + n] = acc;
            acc += deg_sh[k * N_NODES + n];
        }
        deg[n] = acc;
    }
}

__global__ void block_reduce(const int* __restrict__ deg, int* __restrict__ bsum) {
    __shared__ int red[256];
    int b = blockIdx.x, t = threadIdx.x;
    int base = b * SCAN_BLOCK;
    int s = 0;
    for (int i = t; i < SCAN_BLOCK; i += 256) {
        int idx = base + i;
        s += (idx < N_NODES) ? deg[idx] : 0;
    }
    red[t] = s; __syncthreads();
    for (int off = 128; off; off >>= 1) {
        if (t < off) red[t] += red[t + off];
        __syncthreads();
    }
    if (t == 0) bsum[b] = red[0];
}

__global__ void scan_tops(const int* __restrict__ bsum, int* __restrict__ bofs) {
    if (threadIdx.x == 0) {
        int acc = 0;
        for (int i = 0; i < N_SBLK; i++) { bofs[i] = acc; acc += bsum[i]; }
    }
}

__global__ void block_scan(const int* __restrict__ deg, const int* __restrict__ bofs,
                           int* __restrict__ row_start) {
    __shared__ int tmp[SCAN_BLOCK];
    int b = blockIdx.x, t = threadIdx.x;
    int i = b * SCAN_BLOCK + t;
    tmp[t] = (i < N_NODES) ? deg[i] : 0;
    __syncthreads();
    for (int off = 1; off < SCAN_BLOCK; off <<= 1) {
        int add = (t >= off) ? tmp[t - off] : 0;
        __syncthreads();
        tmp[t] += add;
        __syncthreads();
    }
    if (i < N_NODES) row_start[i + 1] = tmp[t] + bofs[b];
    if (i == 0) row_start[0] = 0;
}

__global__ void scatter_kernel(const int* __restrict__ src, const int* __restrict__ dst,
                               const int* __restrict__ pos, const int* __restrict__ row_start,
                               const int* __restrict__ shard_ofs, int* __restrict__ ebuf) {
    int e = blockIdx.x * 256 + threadIdx.x;
    if (e < N_EDGES) {
        int shard = blockIdx.x & (NSHARD - 1);   // must match hist_kernel mapping
        int d = dst[e];
        ebuf[row_start[d] + shard_ofs[shard * N_NODES + d] + pos[e]] = src[e];
    }
}

// ---------------------------------------------------------------------------
// fp32 -> (hi, lo) bf16 split, x input (4 elems / thread)
// ---------------------------------------------------------------------------
__global__ void xsplit(const float* __restrict__ x, ushort_t* __restrict__ xh,
                       ushort_t* __restrict__ xl) {
    int i = blockIdx.x * 256 + threadIdx.x;
    if (i < (N_NODES * DIM) / 4) {
        float4 v = ((const float4*)x)[i];
        uint_t h0,h1,h2,h3,l0,l1,l2,l3;
        bf_split(v.x,h0,l0); bf_split(v.y,h1,l1); bf_split(v.z,h2,l2); bf_split(v.w,h3,l3);
        uint2 ho; ho.x = h0 | (h1 << 16); ho.y = h2 | (h3 << 16);
        uint2 lo; lo.x = l0 | (l1 << 16); lo.y = l2 | (l3 << 16);
        ((uint2*)xh)[i] = ho;
        ((uint2*)xl)[i] = lo;
    }
}

// bf16-hi only for all 6 weight matrices (order: Wl0,Wr0,Wl1,Wr1,Wl2,Wr2)
__global__ void wsplit6(const float* w0, const float* w1, const float* w2,
                        const float* w3, const float* w4, const float* w5,
                        ushort_t* __restrict__ whi) {
    int i = blockIdx.x * 256 + threadIdx.x;
    if (i < 6 * 16384) {
        int ws = i >> 14, off = i & 16383;
        const float* w = (ws == 0) ? w0 : (ws == 1) ? w1 : (ws == 2) ? w2
                       : (ws == 3) ? w3 : (ws == 4) ? w4 : w5;
        whi[i] = (ushort_t)bf_rne(w[off]);
    }
}

// ---------------------------------------------------------------------------
// Mean aggregation over bf16(hi) features: one wave per node.
// 16-lane groups, each lane loads uint4 = 8 bf16 (16 B) -> one row per group,
// 4 edges in flight per wave step. Group-merge via shfl_xor; group 0 writes
// hi/lo split.
// ---------------------------------------------------------------------------
__global__ __launch_bounds__(256) void agg_kernel(const ushort_t* __restrict__ xb,
                                                  const int* __restrict__ row_start,
                                                  const int* __restrict__ ebuf,
                                                  ushort_t* __restrict__ agg_hi,
                                                  ushort_t* __restrict__ agg_lo) {
    int node = blockIdx.x * 4 + (threadIdx.x >> 6);
    if (node >= N_NODES) return;
    int lane = threadIdx.x & 63;
    int grp = lane >> 4, fl = lane & 15;
    int s = row_start[node], e = row_start[node + 1];
    float a0=0.f,a1=0.f,a2=0.f,a3=0.f,a4=0.f,a5=0.f,a6=0.f,a7=0.f;
    const uint4* x8 = (const uint4*)xb;              // row = 16 x uint4 (8 bf16 each)
    for (int i = s; i < e; i += 64) {
        int nloc = e - i; if (nloc > 64) nloc = 64;
        int src_l = (i + lane < e) ? ebuf[i + lane] : 0;
        int jmax = (nloc + 3) & ~3;
        #pragma unroll 2
        for (int j = 0; j < jmax; j += 4) {
            int slot = j + grp;
            int src = __shfl(src_l, slot & 63, 64);
            if (slot < nloc) {
                uint4 v = x8[(size_t)src * 16 + fl];
                a0 += __uint_as_float(v.x << 16);
                a1 += __uint_as_float(v.x & 0xffff0000u);
                a2 += __uint_as_float(v.y << 16);
                a3 += __uint_as_float(v.y & 0xffff0000u);
                a4 += __uint_as_float(v.z << 16);
                a5 += __uint_as_float(v.z & 0xffff0000u);
                a6 += __uint_as_float(v.w << 16);
                a7 += __uint_as_float(v.w & 0xffff0000u);
            }
        }
    }
    // merge the 4 groups (lanes fl, fl+16, fl+32, fl+48)
    a0 += __shfl_xor(a0, 16, 64); a0 += __shfl_xor(a0, 32, 64);
    a1 += __shfl_xor(a1, 16, 64); a1 += __shfl_xor(a1, 32, 64);
    a2 += __shfl_xor(a2, 16, 64); a2 += __shfl_xor(a2, 32, 64);
    a3 += __shfl_xor(a3, 16, 64); a3 += __shfl_xor(a3, 32, 64);
    a4 += __shfl_xor(a4, 16, 64); a4 += __shfl_xor(a4, 32, 64);
    a5 += __shfl_xor(a5, 16, 64); a5 += __shfl_xor(a5, 32, 64);
    a6 += __shfl_xor(a6, 16, 64); a6 += __shfl_xor(a6, 32, 64);
    a7 += __shfl_xor(a7, 16, 64); a7 += __shfl_xor(a7, 32, 64);
    if (grp == 0) {
        float inv = (e > s) ? 1.0f / (float)(e - s) : 0.0f;   // deg==0 -> agg = 0
        float v[8] = {a0*inv,a1*inv,a2*inv,a3*inv,a4*inv,a5*inv,a6*inv,a7*inv};
        uint_t h[8], l[8];
        #pragma unroll
        for (int k = 0; k < 8; k++) bf_split(v[k], h[k], l[k]);
        uint4 ho, lo;
        ho.x = h[0] | (h[1] << 16); ho.y = h[2] | (h[3] << 16);
        ho.z = h[4] | (h[5] << 16); ho.w = h[6] | (h[7] << 16);
        lo.x = l[0] | (l[1] << 16); lo.y = l[2] | (l[3] << 16);
        lo.z = l[4] | (l[5] << 16); lo.w = l[6] | (l[7] << 16);
        ((uint4*)agg_hi)[(size_t)node * 16 + fl] = ho;
        ((uint4*)agg_lo)[(size_t)node * 16 + fl] = lo;
    }
}

// ---------------------------------------------------------------------------
// MFMA GEMM: xout = relu(agg @ Wl^T + x @ Wr^T + b)
// A-side split-bf16 (hi+lo), weights bf16-hi only (4 MFMA terms/tile).
// Block 256 = 4 waves x 16 rows = 64 rows/block; LDS 64KB -> 2 blocks/CU.
// LDS XOR chunk swizzle: chunk ch of row r at ch^(r&7).
// Fragment maps (verified r2): A lane holds M[m=lane&15][k=quad*8+j];
// C/D col=lane&15, row=quad*4+reg.
// ---------------------------------------------------------------------------
__global__ __launch_bounds__(256, 2) void sage_gemm_mfma(
        const ushort_t* __restrict__ agg_hi, const ushort_t* __restrict__ agg_lo,
        const ushort_t* __restrict__ x_hi,   const ushort_t* __restrict__ x_lo,
        const ushort_t* __restrict__ wl_hi,  const ushort_t* __restrict__ wr_hi,
        const float* __restrict__ bias,
        ushort_t* __restrict__ out_hi, ushort_t* __restrict__ out_lo, int nrows) {
    __shared__ ushort_t whi_s[2][16384];    // 64 KB: [0]=Wl_hi, [1]=Wr_hi (swizzled)
    int t = threadIdx.x;
    for (int i = t; i < 4096; i += 256) {   // 2 arrays x 128 rows x 16 chunks
        int a = i >> 11, rem = i & 2047, row = rem >> 4, ch = rem & 15;
        int sw = ch ^ (row & 7);
        const ushort_t* srcp = a ? wr_hi : wl_hi;
        uint4 v = *(const uint4*)(srcp + row * DIM + ch * 8);
        *(uint4*)((char*)&whi_s[a][0] + row * 256 + sw * 16) = v;
    }
    __syncthreads();

    int wave = t >> 6, lane = t & 63;
    int ml = lane & 15, quad = lane >> 4;
    int m0 = blockIdx.x * 64 + wave * 16;
    int row = m0 + ml;
    int rowc = (row < nrows) ? row : (nrows - 1);
    size_t abase = (size_t)rowc * DIM + quad * 8;

    f32x4 acc[8];
    #pragma unroll
    for (int i = 0; i < 8; i++) acc[i] = (f32x4)0.f;

    #pragma unroll
    for (int kc = 0; kc < DIM; kc += 32) {
        bf16x8 Aah = *(const bf16x8*)(agg_hi + abase + kc);
        bf16x8 Aal = *(const bf16x8*)(agg_lo + abase + kc);
        bf16x8 Axh = *(const bf16x8*)(x_hi   + abase + kc);
        bf16x8 Axl = *(const bf16x8*)(x_lo   + abase + kc);
        int kch = (kc >> 3) + quad;          // 16B-chunk index within row
        int sw16 = (kch ^ (ml & 7)) * 16;    // nrow&7 == ml&7 (n0*16 ≡ 0 mod 8)
        #pragma unroll
        for (int n0 = 0; n0 < 8; n0++) {
            int nrow = n0 * 16 + ml;
            bf16x8 b_lh = *(const bf16x8*)((const char*)&whi_s[0][0] + nrow * 256 + sw16);
            bf16x8 b_rh = *(const bf16x8*)((const char*)&whi_s[1][0] + nrow * 256 + sw16);
            f32x4 c = acc[n0];
            c = __builtin_amdgcn_mfma_f32_16x16x32_bf16(Aah, b_lh, c, 0, 0, 0);
            c = __builtin_amdgcn_mfma_f32_16x16x32_bf16(Aal, b_lh, c, 0, 0, 0);
            c = __builtin_amdgcn_mfma_f32_16x16x32_bf16(Axh, b_rh, c, 0, 0, 0);
            c = __builtin_amdgcn_mfma_f32_16x16x32_bf16(Axl, b_rh, c, 0, 0, 0);
            acc[n0] = c;
        }
    }

    #pragma unroll
    for (int n0 = 0; n0 < 8; n0++) {
        int col = n0 * 16 + ml;
        float bv = bias[col];
        #pragma unroll
        for (int r = 0; r < 4; r++) {
            int orow = m0 + quad * 4 + r;
            if (orow < nrows) {
                float v = fmaxf(acc[n0][r] + bv, 0.f);
                uint_t h, l;
                bf_split(v, h, l);
                out_hi[(size_t)orow * DIM + col] = (ushort_t)h;
                out_lo[(size_t)orow * DIM + col] = (ushort_t)l;
            }
        }
    }
}

// ---------------------------------------------------------------------------
// Graph boundaries from sorted batch; fused mean-pool + FC (wave/graph),
// features reconstructed from hi/lo.
// ---------------------------------------------------------------------------
__global__ void graph_bounds(const int* __restrict__ batch, int* __restrict__ gstart) {
    int i = blockIdx.x * 256 + threadIdx.x;
    if (i < N_NODES) {
        int b = batch[i];
        int prev = (i == 0) ? -1 : batch[i - 1];
        for (int g = prev + 1; g <= b; g++) gstart[g] = i;
        if (i == 0) {
            int last = batch[N_NODES - 1];
            for (int g = last + 1; g <= N_GRAPHS; g++) gstart[g] = N_NODES;
        }
    }
}

__global__ __launch_bounds__(256) void pool_fc(const ushort_t* __restrict__ x_hi,
                                               const ushort_t* __restrict__ x_lo,
                                               const int* __restrict__ gstart,
                                               const float* __restrict__ fc_w,
                                               const float* __restrict__ fc_b,
                                               float* __restrict__ out) {
    int g = blockIdx.x * 4 + (threadIdx.x >> 6);
    if (g >= N_GRAPHS) return;
    int lane = threadIdx.x & 63;
    int s = gstart[g], e = gstart[g + 1];
    float ax = 0.f, ay = 0.f;
    const uint_t* xh = (const uint_t*)x_hi;
    const uint_t* xl = (const uint_t*)x_lo;
    for (int i = s; i < e; i++) {
        uint_t h = xh[(size_t)i * 64 + lane];
        uint_t l = xl[(size_t)i * 64 + lane];
        ax += __uint_as_float(h << 16) + __uint_as_float(l << 16);
        ay += __uint_as_float(h & 0xffff0000u) + __uint_as_float(l & 0xffff0000u);
    }
    float inv = (e > s) ? 1.0f / (float)(e - s) : 0.0f;
    const float2* w2 = (const float2*)fc_w;
    float2 w = w2[lane];
    float sres = (ax * w.x + ay * w.y) * inv;
    for (int off = 32; off; off >>= 1) sres += __shfl_down(sres, off, 64);
    if (lane == 0) out[g] = sres + fc_b[0];
}

// ---------------------------------------------------------------------------
extern "C" void kernel_launch(void* const* d_in, const int* in_sizes, int n_in,
                              void* d_out, int out_size, void* d_ws, size_t ws_size,
                              hipStream_t stream) {
    const float* x     = (const float*)d_in[0];
    const int*   ei    = (const int*)d_in[1];
    const int*   batch = (const int*)d_in[2];
    const float* Wl[3] = {(const float*)d_in[3], (const float*)d_in[6], (const float*)d_in[9]};
    const float* bb[3] = {(const float*)d_in[4], (const float*)d_in[7], (const float*)d_in[10]};
    const float* Wr[3] = {(const float*)d_in[5], (const float*)d_in[8], (const float*)d_in[11]};
    const float* fc_w  = (const float*)d_in[12];
    const float* fc_b  = (const float*)d_in[13];
    float* out = (float*)d_out;

    char* p = (char*)d_ws;
    auto alloc = [&](size_t bytes) { char* r = p; p += (bytes + 255) & ~255ull; return r; };
    int* deg_sh    = (int*)alloc((size_t)NSHARD * N_NODES * 4);
    int* shard_ofs = (int*)alloc((size_t)NSHARD * N_NODES * 4);
    int* deg       = (int*)alloc((size_t)N_NODES * 4);
    int* row_start = (int*)alloc((size_t)(N_NODES + 1) * 4);
    int* bsum      = (int*)alloc((size_t)N_SBLK * 4);
    int* bofs      = (int*)alloc((size_t)N_SBLK * 4);
    int* pos       = (int*)alloc((size_t)N_EDGES * 4);
    int* ebuf      = (int*)alloc((size_t)N_EDGES * 4);
    int* gstart    = (int*)alloc((size_t)(N_GRAPHS + 1) * 4);
    const size_t FB = (size_t)N_NODES * DIM * 2;     // feature buffer bytes (bf16)
    ushort_t* agg_hi = (ushort_t*)alloc(FB);
    ushort_t* agg_lo = (ushort_t*)alloc(FB);
    ushort_t* fh[3]  = {(ushort_t*)alloc(FB), (ushort_t*)alloc(FB), (ushort_t*)alloc(FB)};
    ushort_t* fl_[3] = {(ushort_t*)alloc(FB), (ushort_t*)alloc(FB), (ushort_t*)alloc(FB)};
    ushort_t* whi    = (ushort_t*)alloc((size_t)6 * 16384 * 2);

    hipMemsetAsync(deg_sh, 0, (size_t)NSHARD * N_NODES * 4, stream);

    hist_kernel<<<(N_EDGES + 255) / 256, 256, 0, stream>>>(ei + N_EDGES, deg_sh, pos);
    combine_shards<<<(N_NODES + 255) / 256, 256, 0, stream>>>(deg_sh, deg, shard_ofs);
    block_reduce<<<N_SBLK, 256, 0, stream>>>(deg, bsum);
    scan_tops<<<1, 64, 0, stream>>>(bsum, bofs);
    block_scan<<<N_SBLK, SCAN_BLOCK, 0, stream>>>(deg, bofs, row_start);
    scatter_kernel<<<(N_EDGES + 255) / 256, 256, 0, stream>>>(ei, ei + N_EDGES, pos, row_start, shard_ofs, ebuf);
    graph_bounds<<<(N_NODES + 255) / 256, 256, 0, stream>>>(batch, gstart);
    xsplit<<<(N_NODES * DIM / 4 + 255) / 256, 256, 0, stream>>>(x, fh[0], fl_[0]);
    wsplit6<<<(6 * 16384 + 255) / 256, 256, 0, stream>>>(Wl[0], Wr[0], Wl[1], Wr[1], Wl[2], Wr[2], whi);

    // buffers: layer0 in fh[0] -> out fh[1]; layer1 in fh[1] -> out fh[2]; layer2 in fh[2] -> out fh[1]
    int inb = 0;
    for (int l = 0; l < 3; l++) {
        int outb = (l == 0) ? 1 : (l == 1) ? 2 : 1;
        agg_kernel<<<(N_NODES + 3) / 4, 256, 0, stream>>>(fh[inb], row_start, ebuf, agg_hi, agg_lo);
        sage_gemm_mfma<<<(N_NODES + 63) / 64, 256, 0, stream>>>(
            agg_hi, agg_lo, fh[inb], fl_[inb],
            whi + (size_t)(2 * l) * 16384, whi + (size_t)(2 * l + 1) * 16384,
            bb[l], fh[outb], fl_[outb], N_NODES);
        inb = outb;
    }
    pool_fc<<<(N_GRAPHS + 3) / 4, 256, 0, stream>>>(fh[inb], fl_[inb], gstart, fc_w, fc_b, out);
}

// Round 7
// 452.093 us; speedup vs baseline: 2.0435x; 1.0970x over previous
//
#include <hip/hip_runtime.h>

#define N_NODES  50000
#define N_EDGES  1600000
#define DIM      128
#define N_GRAPHS 512
#define SCAN_BLOCK 1024
#define NB1   196        // coarse buckets = ceil(50000/256)
#define B1    256        // phase-1 blocks
#define CHUNK 6250       // edges per phase-1 block (256*6250 = 1.6M exactly)
#define BH_N  (NB1 * B1) // 50176
#define BH_BLK ((BH_N + SCAN_BLOCK - 1) / SCAN_BLOCK)  // 49

typedef unsigned int uint_t;
typedef unsigned short ushort_t;
typedef __attribute__((ext_vector_type(8))) short bf16x8;
typedef __attribute__((ext_vector_type(4))) float f32x4;

__device__ inline uint_t bf_rne(float f) {   // fp32 -> bf16 bits, round-nearest-even
    uint_t u = __float_as_uint(f);
    return (u + 0x7fffu + ((u >> 16) & 1u)) >> 16;
}

// split f into hi (bf16) and lo (bf16 of residual); f ~= hi + lo to ~2^-17 rel
__device__ inline void bf_split(float f, uint_t& h, uint_t& l) {
    h = bf_rne(f);
    float hf = __uint_as_float(h << 16);
    l = bf_rne(f - hf);
}

// ---------------------------------------------------------------------------
// CSR build via MSD 2-phase bucket sort — LDS atomics only, no global atomics.
// P1: coarse bucket = dst>>8 (196 buckets). P2: low byte within bucket.
// Payload packs src (16 bits, N_NODES<65536) | dst_low<<16.
// ---------------------------------------------------------------------------
__global__ __launch_bounds__(256) void p1_count(const int* __restrict__ dst,
                                                int* __restrict__ bh) {
    __shared__ int hist[NB1];
    int b = blockIdx.x, t = threadIdx.x;
    for (int i = t; i < NB1; i += 256) hist[i] = 0;
    __syncthreads();
    int base = b * CHUNK;
    for (int i = t; i < CHUNK; i += 256)
        atomicAdd(&hist[dst[base + i] >> 8], 1);
    __syncthreads();
    for (int i = t; i < NB1; i += 256) bh[i * B1 + b] = hist[i];
}

// hierarchical exclusive scan over bh (BH_N entries) -> ex[i] at ofs[i], ofs[0]=0
__global__ void block_reduce_n(const int* __restrict__ in, int* __restrict__ bsum, int n) {
    __shared__ int red[256];
    int b = blockIdx.x, t = threadIdx.x;
    int base = b * SCAN_BLOCK;
    int s = 0;
    for (int i = t; i < SCAN_BLOCK; i += 256) {
        int idx = base + i;
        s += (idx < n) ? in[idx] : 0;
    }
    red[t] = s; __syncthreads();
    for (int off = 128; off; off >>= 1) {
        if (t < off) red[t] += red[t + off];
        __syncthreads();
    }
    if (t == 0) bsum[b] = red[0];
}

__global__ void scan_tops_n(const int* __restrict__ bsum, int* __restrict__ bofs, int nblk) {
    if (threadIdx.x == 0) {
        int acc = 0;
        for (int i = 0; i < nblk; i++) { bofs[i] = acc; acc += bsum[i]; }
    }
}

__global__ void block_scan_n(const int* __restrict__ in, const int* __restrict__ bofs,
                             int* __restrict__ ofs, int n) {
    __shared__ int tmp[SCAN_BLOCK];
    int b = blockIdx.x, t = threadIdx.x;
    int i = b * SCAN_BLOCK + t;
    tmp[t] = (i < n) ? in[i] : 0;
    __syncthreads();
    for (int off = 1; off < SCAN_BLOCK; off <<= 1) {
        int add = (t >= off) ? tmp[t - off] : 0;
        __syncthreads();
        tmp[t] += add;
        __syncthreads();
    }
    if (i < n) ofs[i + 1] = tmp[t] + bofs[b];
    if (i == 0) ofs[0] = 0;
}

__global__ __launch_bounds__(256) void p1_scatter(const int* __restrict__ src,
                                                  const int* __restrict__ dst,
                                                  const int* __restrict__ bhofs,
                                                  uint_t* __restrict__ ebuf1) {
    __shared__ int cur[NB1];
    int b = blockIdx.x, t = threadIdx.x;
    for (int i = t; i < NB1; i += 256) cur[i] = bhofs[i * B1 + b];
    __syncthreads();
    int base = b * CHUNK;
    for (int i = t; i < CHUNK; i += 256) {
        int d = dst[base + i];
        int pos = atomicAdd(&cur[d >> 8], 1);
        ebuf1[pos] = (uint_t)src[base + i] | ((uint_t)(d & 255) << 16);
    }
}

// one block per coarse bucket: hist over low byte -> row_start + final scatter.
// Unstable ranks OK: equal low byte within a bucket == equal full dst.
__global__ __launch_bounds__(256) void p2_sort(const uint_t* __restrict__ ebuf1,
                                               const int* __restrict__ bhofs,
                                               int* __restrict__ row_start,
                                               int* __restrict__ ebuf) {
    __shared__ int hist[256];
    __shared__ int scn[256];
    __shared__ int cur[256];
    int k = blockIdx.x, t = threadIdx.x;
    int s = bhofs[k * B1];
    int e = (k == NB1 - 1) ? N_EDGES : bhofs[(k + 1) * B1];
    hist[t] = 0;
    __syncthreads();
    for (int i = s + t; i < e; i += 256)
        atomicAdd(&hist[(ebuf1[i] >> 16) & 255], 1);
    __syncthreads();
    int v = hist[t];
    scn[t] = v;
    __syncthreads();
    for (int off = 1; off < 256; off <<= 1) {
        int add = (t >= off) ? scn[t - off] : 0;
        __syncthreads();
        scn[t] += add;
        __syncthreads();
    }
    int ex = scn[t] - v;                 // exclusive scan
    int node = k * 256 + t;
    if (node < N_NODES) row_start[node] = s + ex;
    if (k == NB1 - 1 && t == 0) row_start[N_NODES] = N_EDGES;
    cur[t] = s + ex;
    __syncthreads();
    for (int i = s + t; i < e; i += 256) {
        uint_t p = ebuf1[i];
        int pos = atomicAdd(&cur[(p >> 16) & 255], 1);
        ebuf[pos] = (int)(p & 0xffffu);
    }
}

// ---------------------------------------------------------------------------
// fp32 -> (hi, lo) bf16 split, x input (4 elems / thread)
// ---------------------------------------------------------------------------
__global__ void xsplit(const float* __restrict__ x, ushort_t* __restrict__ xh,
                       ushort_t* __restrict__ xl) {
    int i = blockIdx.x * 256 + threadIdx.x;
    if (i < (N_NODES * DIM) / 4) {
        float4 v = ((const float4*)x)[i];
        uint_t h0,h1,h2,h3,l0,l1,l2,l3;
        bf_split(v.x,h0,l0); bf_split(v.y,h1,l1); bf_split(v.z,h2,l2); bf_split(v.w,h3,l3);
        uint2 ho; ho.x = h0 | (h1 << 16); ho.y = h2 | (h3 << 16);
        uint2 lo; lo.x = l0 | (l1 << 16); lo.y = l2 | (l3 << 16);
        ((uint2*)xh)[i] = ho;
        ((uint2*)xl)[i] = lo;
    }
}

// bf16-hi only for all 6 weight matrices (order: Wl0,Wr0,Wl1,Wr1,Wl2,Wr2)
__global__ void wsplit6(const float* w0, const float* w1, const float* w2,
                        const float* w3, const float* w4, const float* w5,
                        ushort_t* __restrict__ whi) {
    int i = blockIdx.x * 256 + threadIdx.x;
    if (i < 6 * 16384) {
        int ws = i >> 14, off = i & 16383;
        const float* w = (ws == 0) ? w0 : (ws == 1) ? w1 : (ws == 2) ? w2
                       : (ws == 3) ? w3 : (ws == 4) ? w4 : w5;
        whi[i] = (ushort_t)bf_rne(w[off]);
    }
}

// ---------------------------------------------------------------------------
// Mean aggregation over bf16(hi) features: one wave per node.
// 16-lane groups, each lane loads uint4 = 8 bf16 (16 B) -> one row per group,
// 4 edges in flight per wave step. Group-merge via shfl_xor; group 0 writes
// hi/lo split.
// ---------------------------------------------------------------------------
__global__ __launch_bounds__(256) void agg_kernel(const ushort_t* __restrict__ xb,
                                                  const int* __restrict__ row_start,
                                                  const int* __restrict__ ebuf,
                                                  ushort_t* __restrict__ agg_hi,
                                                  ushort_t* __restrict__ agg_lo) {
    int node = blockIdx.x * 4 + (threadIdx.x >> 6);
    if (node >= N_NODES) return;
    int lane = threadIdx.x & 63;
    int grp = lane >> 4, fl = lane & 15;
    int s = row_start[node], e = row_start[node + 1];
    float a0=0.f,a1=0.f,a2=0.f,a3=0.f,a4=0.f,a5=0.f,a6=0.f,a7=0.f;
    const uint4* x8 = (const uint4*)xb;              // row = 16 x uint4 (8 bf16 each)
    for (int i = s; i < e; i += 64) {
        int nloc = e - i; if (nloc > 64) nloc = 64;
        int src_l = (i + lane < e) ? ebuf[i + lane] : 0;
        int jmax = (nloc + 3) & ~3;
        #pragma unroll 2
        for (int j = 0; j < jmax; j += 4) {
            int slot = j + grp;
            int src = __shfl(src_l, slot & 63, 64);
            if (slot < nloc) {
                uint4 v = x8[(size_t)src * 16 + fl];
                a0 += __uint_as_float(v.x << 16);
                a1 += __uint_as_float(v.x & 0xffff0000u);
                a2 += __uint_as_float(v.y << 16);
                a3 += __uint_as_float(v.y & 0xffff0000u);
                a4 += __uint_as_float(v.z << 16);
                a5 += __uint_as_float(v.z & 0xffff0000u);
                a6 += __uint_as_float(v.w << 16);
                a7 += __uint_as_float(v.w & 0xffff0000u);
            }
        }
    }
    a0 += __shfl_xor(a0, 16, 64); a0 += __shfl_xor(a0, 32, 64);
    a1 += __shfl_xor(a1, 16, 64); a1 += __shfl_xor(a1, 32, 64);
    a2 += __shfl_xor(a2, 16, 64); a2 += __shfl_xor(a2, 32, 64);
    a3 += __shfl_xor(a3, 16, 64); a3 += __shfl_xor(a3, 32, 64);
    a4 += __shfl_xor(a4, 16, 64); a4 += __shfl_xor(a4, 32, 64);
    a5 += __shfl_xor(a5, 16, 64); a5 += __shfl_xor(a5, 32, 64);
    a6 += __shfl_xor(a6, 16, 64); a6 += __shfl_xor(a6, 32, 64);
    a7 += __shfl_xor(a7, 16, 64); a7 += __shfl_xor(a7, 32, 64);
    if (grp == 0) {
        float inv = (e > s) ? 1.0f / (float)(e - s) : 0.0f;   // deg==0 -> agg = 0
        float v[8] = {a0*inv,a1*inv,a2*inv,a3*inv,a4*inv,a5*inv,a6*inv,a7*inv};
        uint_t h[8], l[8];
        #pragma unroll
        for (int k = 0; k < 8; k++) bf_split(v[k], h[k], l[k]);
        uint4 ho, lo;
        ho.x = h[0] | (h[1] << 16); ho.y = h[2] | (h[3] << 16);
        ho.z = h[4] | (h[5] << 16); ho.w = h[6] | (h[7] << 16);
        lo.x = l[0] | (l[1] << 16); lo.y = l[2] | (l[3] << 16);
        lo.z = l[4] | (l[5] << 16); lo.w = l[6] | (l[7] << 16);
        ((uint4*)agg_hi)[(size_t)node * 16 + fl] = ho;
        ((uint4*)agg_lo)[(size_t)node * 16 + fl] = lo;
    }
}

// ---------------------------------------------------------------------------
// MFMA GEMM: xout = relu(agg @ Wl^T + x @ Wr^T + b)
// A-side split-bf16 (hi+lo), weights bf16-hi only (4 MFMA terms/tile).
// Block 256 = 4 waves x 16 rows = 64 rows/block; LDS 64KB -> 2 blocks/CU.
// LDS XOR chunk swizzle: chunk ch of row r at ch^(r&7).
// Fragment maps (verified r2): A lane holds M[m=lane&15][k=quad*8+j];
// C/D col=lane&15, row=quad*4+reg.
// ---------------------------------------------------------------------------
__global__ __launch_bounds__(256, 2) void sage_gemm_mfma(
        const ushort_t* __restrict__ agg_hi, const ushort_t* __restrict__ agg_lo,
        const ushort_t* __restrict__ x_hi,   const ushort_t* __restrict__ x_lo,
        const ushort_t* __restrict__ wl_hi,  const ushort_t* __restrict__ wr_hi,
        const float* __restrict__ bias,
        ushort_t* __restrict__ out_hi, ushort_t* __restrict__ out_lo, int nrows) {
    __shared__ ushort_t whi_s[2][16384];    // 64 KB: [0]=Wl_hi, [1]=Wr_hi (swizzled)
    int t = threadIdx.x;
    for (int i = t; i < 4096; i += 256) {   // 2 arrays x 128 rows x 16 chunks
        int a = i >> 11, rem = i & 2047, row = rem >> 4, ch = rem & 15;
        int sw = ch ^ (row & 7);
        const ushort_t* srcp = a ? wr_hi : wl_hi;
        uint4 v = *(const uint4*)(srcp + row * DIM + ch * 8);
        *(uint4*)((char*)&whi_s[a][0] + row * 256 + sw * 16) = v;
    }
    __syncthreads();

    int wave = t >> 6, lane = t & 63;
    int ml = lane & 15, quad = lane >> 4;
    int m0 = blockIdx.x * 64 + wave * 16;
    int row = m0 + ml;
    int rowc = (row < nrows) ? row : (nrows - 1);
    size_t abase = (size_t)rowc * DIM + quad * 8;

    f32x4 acc[8];
    #pragma unroll
    for (int i = 0; i < 8; i++) acc[i] = (f32x4)0.f;

    #pragma unroll
    for (int kc = 0; kc < DIM; kc += 32) {
        bf16x8 Aah = *(const bf16x8*)(agg_hi + abase + kc);
        bf16x8 Aal = *(const bf16x8*)(agg_lo + abase + kc);
        bf16x8 Axh = *(const bf16x8*)(x_hi   + abase + kc);
        bf16x8 Axl = *(const bf16x8*)(x_lo   + abase + kc);
        int kch = (kc >> 3) + quad;          // 16B-chunk index within row
        int sw16 = (kch ^ (ml & 7)) * 16;    // nrow&7 == ml&7 (n0*16 ≡ 0 mod 8)
        #pragma unroll
        for (int n0 = 0; n0 < 8; n0++) {
            int nrow = n0 * 16 + ml;
            bf16x8 b_lh = *(const bf16x8*)((const char*)&whi_s[0][0] + nrow * 256 + sw16);
            bf16x8 b_rh = *(const bf16x8*)((const char*)&whi_s[1][0] + nrow * 256 + sw16);
            f32x4 c = acc[n0];
            c = __builtin_amdgcn_mfma_f32_16x16x32_bf16(Aah, b_lh, c, 0, 0, 0);
            c = __builtin_amdgcn_mfma_f32_16x16x32_bf16(Aal, b_lh, c, 0, 0, 0);
            c = __builtin_amdgcn_mfma_f32_16x16x32_bf16(Axh, b_rh, c, 0, 0, 0);
            c = __builtin_amdgcn_mfma_f32_16x16x32_bf16(Axl, b_rh, c, 0, 0, 0);
            acc[n0] = c;
        }
    }

    #pragma unroll
    for (int n0 = 0; n0 < 8; n0++) {
        int col = n0 * 16 + ml;
        float bv = bias[col];
        #pragma unroll
        for (int r = 0; r < 4; r++) {
            int orow = m0 + quad * 4 + r;
            if (orow < nrows) {
                float v = fmaxf(acc[n0][r] + bv, 0.f);
                uint_t h, l;
                bf_split(v, h, l);
                out_hi[(size_t)orow * DIM + col] = (ushort_t)h;
                out_lo[(size_t)orow * DIM + col] = (ushort_t)l;
            }
        }
    }
}

// ---------------------------------------------------------------------------
// Graph boundaries from sorted batch; fused mean-pool + FC (wave/graph),
// features reconstructed from hi/lo.
// ---------------------------------------------------------------------------
__global__ void graph_bounds(const int* __restrict__ batch, int* __restrict__ gstart) {
    int i = blockIdx.x * 256 + threadIdx.x;
    if (i < N_NODES) {
        int b = batch[i];
        int prev = (i == 0) ? -1 : batch[i - 1];
        for (int g = prev + 1; g <= b; g++) gstart[g] = i;
        if (i == 0) {
            int last = batch[N_NODES - 1];
            for (int g = last + 1; g <= N_GRAPHS; g++) gstart[g] = N_NODES;
        }
    }
}

__global__ __launch_bounds__(256) void pool_fc(const ushort_t* __restrict__ x_hi,
                                               const ushort_t* __restrict__ x_lo,
                                               const int* __restrict__ gstart,
                                               const float* __restrict__ fc_w,
                                               const float* __restrict__ fc_b,
                                               float* __restrict__ out) {
    int g = blockIdx.x * 4 + (threadIdx.x >> 6);
    if (g >= N_GRAPHS) return;
    int lane = threadIdx.x & 63;
    int s = gstart[g], e = gstart[g + 1];
    float ax = 0.f, ay = 0.f;
    const uint_t* xh = (const uint_t*)x_hi;
    const uint_t* xl = (const uint_t*)x_lo;
    for (int i = s; i < e; i++) {
        uint_t h = xh[(size_t)i * 64 + lane];
        uint_t l = xl[(size_t)i * 64 + lane];
        ax += __uint_as_float(h << 16) + __uint_as_float(l << 16);
        ay += __uint_as_float(h & 0xffff0000u) + __uint_as_float(l & 0xffff0000u);
    }
    float inv = (e > s) ? 1.0f / (float)(e - s) : 0.0f;
    const float2* w2 = (const float2*)fc_w;
    float2 w = w2[lane];
    float sres = (ax * w.x + ay * w.y) * inv;
    for (int off = 32; off; off >>= 1) sres += __shfl_down(sres, off, 64);
    if (lane == 0) out[g] = sres + fc_b[0];
}

// ---------------------------------------------------------------------------
extern "C" void kernel_launch(void* const* d_in, const int* in_sizes, int n_in,
                              void* d_out, int out_size, void* d_ws, size_t ws_size,
                              hipStream_t stream) {
    const float* x     = (const float*)d_in[0];
    const int*   ei    = (const int*)d_in[1];
    const int*   batch = (const int*)d_in[2];
    const float* Wl[3] = {(const float*)d_in[3], (const float*)d_in[6], (const float*)d_in[9]};
    const float* bb[3] = {(const float*)d_in[4], (const float*)d_in[7], (const float*)d_in[10]};
    const float* Wr[3] = {(const float*)d_in[5], (const float*)d_in[8], (const float*)d_in[11]};
    const float* fc_w  = (const float*)d_in[12];
    const float* fc_b  = (const float*)d_in[13];
    float* out = (float*)d_out;

    char* p = (char*)d_ws;
    auto alloc = [&](size_t bytes) { char* r = p; p += (bytes + 255) & ~255ull; return r; };
    int* bh        = (int*)alloc((size_t)BH_N * 4);
    int* bhofs     = (int*)alloc((size_t)(BH_N + 1) * 4);
    int* bsum      = (int*)alloc((size_t)BH_BLK * 4);
    int* bofs      = (int*)alloc((size_t)BH_BLK * 4);
    uint_t* ebuf1  = (uint_t*)alloc((size_t)N_EDGES * 4);
    int* ebuf      = (int*)alloc((size_t)N_EDGES * 4);
    int* row_start = (int*)alloc((size_t)(N_NODES + 1) * 4);
    int* gstart    = (int*)alloc((size_t)(N_GRAPHS + 1) * 4);
    const size_t FB = (size_t)N_NODES * DIM * 2;     // feature buffer bytes (bf16)
    ushort_t* agg_hi = (ushort_t*)alloc(FB);
    ushort_t* agg_lo = (ushort_t*)alloc(FB);
    ushort_t* fh[3]  = {(ushort_t*)alloc(FB), (ushort_t*)alloc(FB), (ushort_t*)alloc(FB)};
    ushort_t* fl_[3] = {(ushort_t*)alloc(FB), (ushort_t*)alloc(FB), (ushort_t*)alloc(FB)};
    ushort_t* whi    = (ushort_t*)alloc((size_t)6 * 16384 * 2);

    const int* src = ei;
    const int* dst = ei + N_EDGES;

    p1_count<<<B1, 256, 0, stream>>>(dst, bh);
    block_reduce_n<<<BH_BLK, 256, 0, stream>>>(bh, bsum, BH_N);
    scan_tops_n<<<1, 64, 0, stream>>>(bsum, bofs, BH_BLK);
    block_scan_n<<<BH_BLK, SCAN_BLOCK, 0, stream>>>(bh, bofs, bhofs, BH_N);
    p1_scatter<<<B1, 256, 0, stream>>>(src, dst, bhofs, ebuf1);
    p2_sort<<<NB1, 256, 0, stream>>>(ebuf1, bhofs, row_start, ebuf);
    graph_bounds<<<(N_NODES + 255) / 256, 256, 0, stream>>>(batch, gstart);
    xsplit<<<(N_NODES * DIM / 4 + 255) / 256, 256, 0, stream>>>(x, fh[0], fl_[0]);
    wsplit6<<<(6 * 16384 + 255) / 256, 256, 0, stream>>>(Wl[0], Wr[0], Wl[1], Wr[1], Wl[2], Wr[2], whi);

    // buffers: layer0 in fh[0] -> out fh[1]; layer1 in fh[1] -> out fh[2]; layer2 in fh[2] -> out fh[1]
    int inb = 0;
    for (int l = 0; l < 3; l++) {
        int outb = (l == 0) ? 1 : (l == 1) ? 2 : 1;
        agg_kernel<<<(N_NODES + 3) / 4, 256, 0, stream>>>(fh[inb], row_start, ebuf, agg_hi, agg_lo);
        sage_gemm_mfma<<<(N_NODES + 63) / 64, 256, 0, stream>>>(
            agg_hi, agg_lo, fh[inb], fl_[inb],
            whi + (size_t)(2 * l) * 16384, whi + (size_t)(2 * l + 1) * 16384,
            bb[l], fh[outb], fl_[outb], N_NODES);
        inb = outb;
    }
    pool_fc<<<(N_GRAPHS + 3) / 4, 256, 0, stream>>>(fh[inb], fl_[inb], gstart, fc_w, fc_b, out);
}